// Round 18
// baseline (212.386 us; speedup 1.0000x reference)
//
#include <hip/hip_runtime.h>
#include <hip/hip_bf16.h>
#include <stdint.h>
#include <stddef.h>

#define NB 16
#define NS 1024
#define ND 512
#define NH 8
#define NDFF 2048
#define NTOK (NB * NS)
#define LDK 1024  // fused QK row stride

typedef __bf16 bf16;
typedef __attribute__((ext_vector_type(2))) __bf16 bf16x2;
typedef __attribute__((ext_vector_type(4))) __bf16 bf16x4;
typedef __attribute__((ext_vector_type(8))) __bf16 bf16x8;
typedef __attribute__((ext_vector_type(4))) float f32x4;

__device__ __forceinline__ void async_copy16(const void* g, void* l) {
  __builtin_amdgcn_global_load_lds(
      (const __attribute__((address_space(1))) void*)g,
      (__attribute__((address_space(3))) void*)l,
      16, 0, 0);
}

// ---------------- all fp32 -> bf16 conversions in one kernel ----------------
__global__ __launch_bounds__(256) void cvt_all(
    const float* __restrict__ x, const float* __restrict__ wq,
    const float* __restrict__ wk, const float* __restrict__ wv,
    const float* __restrict__ wfc, const float* __restrict__ w1f,
    const float* __restrict__ w2f,
    bf16* __restrict__ xb, bf16* __restrict__ w3b,
    bf16* __restrict__ wfcb, bf16* __restrict__ w1fb, bf16* __restrict__ w2fb) {
  constexpr int C0 = 2097152, C1 = C0 + 65536, C2 = C1 + 65536, C3 = C2 + 65536,
                C4 = C3 + 65536, C5 = C4 + 262144;
  const int i = blockIdx.x * 256 + threadIdx.x;
  const float* s;
  bf16* d;
  int base;
  if (i < C0)      { s = x;   d = xb;            base = 0;  }
  else if (i < C1) { s = wq;  d = w3b;           base = C0; }
  else if (i < C2) { s = wk;  d = w3b + 262144;  base = C1; }
  else if (i < C3) { s = wv;  d = w3b + 524288;  base = C2; }
  else if (i < C4) { s = wfc; d = wfcb;          base = C3; }
  else if (i < C5) { s = w1f; d = w1fb;          base = C4; }
  else             { s = w2f; d = w2fb;          base = C5; }
  const int k = i - base;
  const float4 v = ((const float4*)s)[k];
  bf16x4 o = {(bf16)v.x, (bf16)v.y, (bf16)v.z, (bf16)v.w};
  ((bf16x4*)d)[k] = o;
}

// ---------------- concat 3 bias vectors (512 each) ----------------
__global__ __launch_bounds__(512) void concat3(const float* __restrict__ a,
                                               const float* __restrict__ b,
                                               const float* __restrict__ c,
                                               float* __restrict__ o) {
  const int t = threadIdx.x;
  o[t] = a[t];
  o[512 + t] = b[t];
  o[1024 + t] = c[t];
}

// LDS chunk swizzle: within a 16-row x 4-chunk (64B-row) segment, slot (r,c)
// holds global chunk c ^ ((r>>1)&3) (source-pre-swizzled, rule 21).
__device__ __forceinline__ int swz_src_col(int lane) {
  const int r = lane >> 2, c = lane & 3;
  return (c ^ ((r >> 1) & 3)) * 8;
}

// ---------------- GEMM 256x128, BK=32, 512 thr = 8 waves (4m x 2n), wave 64x64 ----
// Counted-vmcnt double-buffer schedule. XCD-swizzled (grids %8==0).
// QKV mode: N=1536; cols<1024 -> qkb (stride 1024); cols>=1024 -> V^T to Cvt.
// RESB mode: bf16 out = acc + bias + bf16 residual (pre-LN2 sum).
template <bool RELU, bool QKV, bool RESB>
__global__ __launch_bounds__(512, 4) void gemm_bt(
    const bf16* __restrict__ A, const bf16* __restrict__ Bw,
    const float* __restrict__ bias, bf16* __restrict__ Cb,
    bf16* __restrict__ Cvt, const bf16* __restrict__ residb,
    int M, int N, int K) {
  __shared__ bf16 As[2][256 * 32];  // 16 KB per buffer
  __shared__ bf16 Bs[2][128 * 32];  // 8 KB per buffer
  const int tid = threadIdx.x;
  const int lane = tid & 63;
  const int wid = tid >> 6;  // 0..7

  const int nwg = gridDim.x * gridDim.y;
  int id = blockIdx.y * gridDim.x + blockIdx.x;
  id = (id & 7) * (nwg >> 3) + (id >> 3);
  const int tn = id % gridDim.x, tm = id / gridDim.x;

  const int wm = wid >> 1, wn = wid & 1;  // wave tile: rows wm*64, cols wn*64
  const int lr = lane & 15, hi2 = lane >> 4;
  const int lkA = ((hi2 ^ ((lr >> 1) & 3)) << 3);  // swizzled read chunk
  const int srow = lane >> 2, scol = swz_src_col(lane);

  f32x4 acc[4][4] = {};

  const bf16* Abase = A + (size_t)(tm * 256 + srow) * K + scol;
  const bf16* Bbase = Bw + (size_t)(tn * 128 + srow) * K + scol;
  const int kiters = K >> 5;

  // 24 chunk-copies (16 A segs + 8 B segs), 3 per wave
  auto stage = [&](int buf, int kb) {
#pragma unroll
    for (int t = 0; t < 3; ++t) {
      const int c = wid * 3 + t;
      if (c < 16) {
        async_copy16(Abase + (size_t)c * 16 * K + kb * 32, &As[buf][c * 512]);
      } else {
        const int s = c - 16;
        async_copy16(Bbase + (size_t)s * 16 * K + kb * 32, &Bs[buf][s * 512]);
      }
    }
  };

  stage(0, 0);

  int buf = 0;
  for (int kb = 0; kb < kiters; ++kb) {
    if (kb + 1 < kiters) {
      stage(buf ^ 1, kb + 1);
      asm volatile("s_waitcnt vmcnt(3)" ::: "memory");  // wait prev tile only
    } else {
      asm volatile("s_waitcnt vmcnt(0)" ::: "memory");
    }
    __builtin_amdgcn_s_barrier();
    __builtin_amdgcn_sched_barrier(0);

    bf16x8 af[4], bfr[4];
#pragma unroll
    for (int i = 0; i < 4; ++i)
      af[i] = *(const bf16x8*)&As[buf][(wm * 64 + i * 16 + lr) * 32 + lkA];
#pragma unroll
    for (int j = 0; j < 4; ++j)
      bfr[j] = *(const bf16x8*)&Bs[buf][(wn * 64 + j * 16 + lr) * 32 + lkA];
#pragma unroll
    for (int i = 0; i < 4; ++i)
#pragma unroll
      for (int j = 0; j < 4; ++j)
        acc[i][j] = __builtin_amdgcn_mfma_f32_16x16x32_bf16(af[i], bfr[j], acc[i][j], 0, 0, 0);

    __builtin_amdgcn_s_barrier();
    __builtin_amdgcn_sched_barrier(0);
    buf ^= 1;
  }

#pragma unroll
  for (int i = 0; i < 4; ++i) {
    const int row0 = tm * 256 + wm * 64 + i * 16 + hi2 * 4;
#pragma unroll
    for (int j = 0; j < 4; ++j) {
      const int col = tn * 128 + wn * 64 + j * 16 + lr;
      const float bcol = bias[col];
      if (QKV && col >= 1024) {
        bf16x4 ov;
#pragma unroll
        for (int r = 0; r < 4; ++r) ov[r] = (bf16)(acc[i][j][r] + bcol);
        *(bf16x4*)&Cvt[(size_t)(col - 1024) * M + row0] = ov;
      } else if (RESB) {
#pragma unroll
        for (int r = 0; r < 4; ++r) {
          const size_t idx = (size_t)(row0 + r) * N + col;
          Cb[idx] = (bf16)(acc[i][j][r] + bcol + (float)residb[idx]);
        }
      } else {
        const int strideN = QKV ? 1024 : N;
#pragma unroll
        for (int r = 0; r < 4; ++r) {
          float c = acc[i][j][r] + bcol;
          if (RELU) c = fmaxf(c, 0.f);
          Cb[(size_t)(row0 + r) * strideN + col] = (bf16)c;
        }
      }
    }
  }
}

// ---------------- GEMM (BM=64, BN=N=512) + bias + bf16 resid + fused LayerNorm ----------------
// K=512 only (fc+LN1). Writes LN output ONCE as bf16 (FFN1 input AND FFN2 resid).
__global__ __launch_bounds__(512) void gemm_ln(
    const bf16* __restrict__ A, const bf16* __restrict__ Bw,
    const float* __restrict__ bias, const bf16* __restrict__ resid,
    bf16* __restrict__ outB,
    const float* __restrict__ gam, const float* __restrict__ bet,
    float eps, int K) {
  __shared__ bf16 As[2][64 * 32];
  __shared__ bf16 Bs[2][512 * 32];
  __shared__ float red[8 * 32 * 2];
  const int tid = threadIdx.x;
  const int lane = tid & 63;
  const int wid = tid >> 6;
  const int wm = wid >> 2, wn = wid & 3;
  const int lr = lane & 15, hi2 = lane >> 4;
  const int lkA = ((hi2 ^ ((lr >> 1) & 3)) << 3);
  const int tm = blockIdx.x;

  f32x4 acc[2][8] = {};
  const int kiters = K >> 5;
  const int r4 = lane >> 2, c4 = swz_src_col(lane);

  auto stage = [&](int buf, int kb) {
    if (wid < 4) {
      async_copy16(A + (size_t)(tm * 64 + wid * 16 + r4) * K + kb * 32 + c4,
                   &As[buf][wid * 16 * 32]);
#pragma unroll
      for (int i = 0; i < 3; ++i) {
        const int s = wid * 3 + i;
        async_copy16(Bw + (size_t)(s * 16 + r4) * K + kb * 32 + c4, &Bs[buf][s * 16 * 32]);
      }
    } else {
#pragma unroll
      for (int i = 0; i < 5; ++i) {
        const int s = 12 + (wid - 4) * 5 + i;
        async_copy16(Bw + (size_t)(s * 16 + r4) * K + kb * 32 + c4, &Bs[buf][s * 16 * 32]);
      }
    }
  };

  stage(0, 0);

  int buf = 0;
  for (int kb = 0; kb < kiters; ++kb) {
    if (kb + 1 < kiters) {
      stage(buf ^ 1, kb + 1);
      if (wid < 4) asm volatile("s_waitcnt vmcnt(4)" ::: "memory");
      else         asm volatile("s_waitcnt vmcnt(5)" ::: "memory");
    } else {
      asm volatile("s_waitcnt vmcnt(0)" ::: "memory");
    }
    __builtin_amdgcn_s_barrier();
    __builtin_amdgcn_sched_barrier(0);

    bf16x8 af[2], bfr[8];
#pragma unroll
    for (int i = 0; i < 2; ++i)
      af[i] = *(const bf16x8*)&As[buf][(wm * 32 + i * 16 + lr) * 32 + lkA];
#pragma unroll
    for (int j = 0; j < 8; ++j)
      bfr[j] = *(const bf16x8*)&Bs[buf][(wn * 128 + j * 16 + lr) * 32 + lkA];
#pragma unroll
    for (int i = 0; i < 2; ++i)
#pragma unroll
      for (int j = 0; j < 8; ++j)
        acc[i][j] = __builtin_amdgcn_mfma_f32_16x16x32_bf16(af[i], bfr[j], acc[i][j], 0, 0, 0);

    __builtin_amdgcn_s_barrier();
    __builtin_amdgcn_sched_barrier(0);
    buf ^= 1;
  }

  float bi[8];
#pragma unroll
  for (int j = 0; j < 8; ++j) bi[j] = bias[wn * 128 + j * 16 + lr];
#pragma unroll
  for (int i = 0; i < 2; ++i)
#pragma unroll
    for (int r = 0; r < 4; ++r) {
      const int rowg = tm * 64 + wm * 32 + i * 16 + hi2 * 4 + r;
#pragma unroll
      for (int j = 0; j < 8; ++j)
        acc[i][j][r] += bi[j] + (float)resid[(size_t)rowg * ND + wn * 128 + j * 16 + lr];
    }
#pragma unroll
  for (int i = 0; i < 2; ++i)
#pragma unroll
    for (int r = 0; r < 4; ++r) {
      float s = 0.f, s2 = 0.f;
#pragma unroll
      for (int j = 0; j < 8; ++j) {
        const float v = acc[i][j][r];
        s += v;
        s2 += v * v;
      }
#pragma unroll
      for (int o = 1; o < 16; o <<= 1) {
        s += __shfl_xor(s, o, 64);
        s2 += __shfl_xor(s2, o, 64);
      }
      if (lr == 0) {
        red[(wid * 32 + i * 16 + hi2 * 4 + r) * 2 + 0] = s;
        red[(wid * 32 + i * 16 + hi2 * 4 + r) * 2 + 1] = s2;
      }
    }
  __syncthreads();
  float g8[8], be8[8];
#pragma unroll
  for (int j = 0; j < 8; ++j) {
    g8[j] = gam[wn * 128 + j * 16 + lr];
    be8[j] = bet[wn * 128 + j * 16 + lr];
  }
#pragma unroll
  for (int i = 0; i < 2; ++i)
#pragma unroll
    for (int r = 0; r < 4; ++r) {
      const int rlw = i * 16 + hi2 * 4 + r;
      float S = 0.f, S2 = 0.f;
#pragma unroll
      for (int q = 0; q < 4; ++q) {
        S += red[((wm * 4 + q) * 32 + rlw) * 2 + 0];
        S2 += red[((wm * 4 + q) * 32 + rlw) * 2 + 1];
      }
      const float mu = S * (1.f / ND);
      const float rstd = rsqrtf(S2 * (1.f / ND) - mu * mu + eps);
      const int rowg = tm * 64 + wm * 32 + rlw;
#pragma unroll
      for (int j = 0; j < 8; ++j) {
        const float ln = (acc[i][j][r] - mu) * rstd * g8[j] + be8[j];
        outB[(size_t)rowg * ND + wn * 128 + j * 16 + lr] = (bf16)ln;
      }
    }
}

// ---------------- LayerNorm: bf16 in -> fp32 out, one wave per row of 512 ----------------
__global__ __launch_bounds__(256) void layernorm_b(
    const bf16* __restrict__ in, const float* __restrict__ gam,
    const float* __restrict__ bet, float eps, float* __restrict__ outf) {
  const int row = blockIdx.x * 4 + (threadIdx.x >> 6);
  const int lane = threadIdx.x & 63;
  const bf16x8 v = ((const bf16x8*)(in + (size_t)row * ND))[lane];
  float f[8];
  float s = 0.f, s2 = 0.f;
#pragma unroll
  for (int e = 0; e < 8; ++e) {
    f[e] = (float)v[e];
    s += f[e];
    s2 += f[e] * f[e];
  }
#pragma unroll
  for (int off = 1; off < 64; off <<= 1) {
    s += __shfl_xor(s, off, 64);
    s2 += __shfl_xor(s2, off, 64);
  }
  const float mu = s * (1.f / ND);
  const float var = s2 * (1.f / ND) - mu * mu;
  const float rstd = rsqrtf(var + eps);
  const float4 g0 = ((const float4*)gam)[lane * 2];
  const float4 g1 = ((const float4*)gam)[lane * 2 + 1];
  const float4 b0 = ((const float4*)bet)[lane * 2];
  const float4 b1 = ((const float4*)bet)[lane * 2 + 1];
  float4 o0, o1;
  o0.x = (f[0] - mu) * rstd * g0.x + b0.x;
  o0.y = (f[1] - mu) * rstd * g0.y + b0.y;
  o0.z = (f[2] - mu) * rstd * g0.z + b0.z;
  o0.w = (f[3] - mu) * rstd * g0.w + b0.w;
  o1.x = (f[4] - mu) * rstd * g1.x + b1.x;
  o1.y = (f[5] - mu) * rstd * g1.y + b1.y;
  o1.z = (f[6] - mu) * rstd * g1.z + b1.z;
  o1.w = (f[7] - mu) * rstd * g1.w + b1.w;
  float* op = outf + (size_t)row * ND;
  ((float4*)op)[lane * 2] = o0;
  ((float4*)op)[lane * 2 + 1] = o1;
}

// ---------------- Flash attention, causal diag -current ----------------
// QBLK=256: 512 thr = 8 waves, wave w owns q rows {q0+16w, q0+128+16w} (2 frags).
// K/V staged once per 256 q. SCL2 folded into Q fragments. Wholly-masked frags
// skipped wave-uniformly. Pw reused serially across frags (per-wave, in-order LDS).
__global__ __launch_bounds__(512) void attn_k(
    const bf16* __restrict__ QKg, const bf16* __restrict__ VTg,
    bf16* __restrict__ O, const int* __restrict__ curp) {
  const int current = *curp;
  const int bh = blockIdx.x;
  const int b = bh >> 3, h = bh & 7;
  const int q0 = (gridDim.y - 1 - blockIdx.y) * 256;  // heavy-first dispatch
  const int tid = threadIdx.x, lane = tid & 63, wid = tid >> 6;  // wid 0..7
  const int lr = lane & 15, hi2 = lane >> 4, lk = hi2 * 8;

  __shared__ bf16 Kt[2][64 * 64];
  __shared__ bf16 Vt2[2][64 * 64];
  __shared__ bf16 Pw[8][16 * 76];

  const float SCL2 = 0.18033688f;  // (1/sqrt(64)) * log2(e), folded into Q

  bf16x8 aq0[2], aq1[2];
#pragma unroll
  for (int f = 0; f < 2; ++f) {
    const size_t qoff =
        (size_t)(b * NS + q0 + f * 128 + wid * 16 + lr) * LDK + h * 64 + lk;
    const bf16x8 r0 = *(const bf16x8*)&QKg[qoff];
    const bf16x8 r1 = *(const bf16x8*)&QKg[qoff + 32];
#pragma unroll
    for (int e = 0; e < 8; ++e) {
      aq0[f][e] = (bf16)((float)r0[e] * SCL2);
      aq1[f][e] = (bf16)((float)r1[e] * SCL2);
    }
  }

  f32x4 acc[2][4] = {};
  float m_run[2] = {-1e30f, -1e30f}, l_run[2] = {0.f, 0.f};

  int kmax = q0 + 255 - current;
  if (kmax > NS - 1) kmax = NS - 1;
  const int nkt = (kmax >= 0) ? ((kmax >> 6) + 1) : 0;

  const int kchunk = (lane & 7) ^ (lane >> 3);  // K source pre-swizzle
  const int vdv = wid * 8 + (lane >> 3);        // V dest dv row
  const int vkeyc = ((lane & 7) ^ (lane >> 3)) * 8;  // V source key chunk (swz)

  auto stageKV = [&](int kt_, int buf_) {
    const int k0_ = kt_ * 64;
    const int rloc = wid * 8 + (lane >> 3);
    async_copy16(&QKg[(size_t)(b * NS + k0_ + rloc) * LDK + 512 + h * 64 + kchunk * 8],
                 &Kt[buf_][wid * 512]);
    async_copy16(&VTg[(size_t)(h * 64 + vdv) * NTOK + b * NS + k0_ + vkeyc],
                 &Vt2[buf_][wid * 512]);
  };

  if (nkt > 0) stageKV(0, 0);

  for (int kt = 0; kt < nkt; ++kt) {
    const int buf = kt & 1;
    if (kt + 1 < nkt) {
      stageKV(kt + 1, buf ^ 1);
      asm volatile("s_waitcnt vmcnt(2)" ::: "memory");
    } else {
      asm volatile("s_waitcnt vmcnt(0)" ::: "memory");
    }
    __builtin_amdgcn_s_barrier();
    __builtin_amdgcn_sched_barrier(0);

    const int k0 = kt * 64;
    const bf16* Ktb = &Kt[buf][0];
    const bf16* Vtb = &Vt2[buf][0];

#pragma unroll
    for (int f = 0; f < 2; ++f) {
      const int qbase = q0 + f * 128 + wid * 16;  // wave-uniform
      if (k0 + current > qbase + 15) continue;    // frag fully masked: skip
      const int qv = qbase + lr;

      f32x4 sf[4];
      __builtin_amdgcn_s_setprio(1);
#pragma unroll
      for (int kc = 0; kc < 4; ++kc) {
        const int row = kc * 16 + lr;
        const int idx0 = row * 64 + ((hi2 ^ (lr & 7)) << 3);
        f32x4 z = {};
        const bf16x8 bk0 = *(const bf16x8*)&Ktb[idx0];
        const bf16x8 bk1 = *(const bf16x8*)&Ktb[idx0 ^ 32];
        z = __builtin_amdgcn_mfma_f32_16x16x32_bf16(bk0, aq0[f], z, 0, 0, 0);
        z = __builtin_amdgcn_mfma_f32_16x16x32_bf16(bk1, aq1[f], z, 0, 0, 0);
        sf[kc] = z;  // already log2-domain (SCL2 folded into Q)
      }
      __builtin_amdgcn_s_setprio(0);

      float sv[16];
      float mx = -1e30f;
      const bool full = (k0 + 63 + current <= qbase);
      if (full) {
#pragma unroll
        for (int kc = 0; kc < 4; ++kc)
#pragma unroll
          for (int r = 0; r < 4; ++r) {
            const float s = sf[kc][r];
            sv[kc * 4 + r] = s;
            mx = fmaxf(mx, s);
          }
      } else {
        const int keyb = k0 + hi2 * 4;
#pragma unroll
        for (int kc = 0; kc < 4; ++kc)
#pragma unroll
          for (int r = 0; r < 4; ++r) {
            const int key = keyb + kc * 16 + r;
            const float s = (key + current <= qv) ? sf[kc][r] : -3.0e38f;
            sv[kc * 4 + r] = s;
            mx = fmaxf(mx, s);
          }
      }
      mx = fmaxf(mx, __shfl_xor(mx, 16, 64));
      mx = fmaxf(mx, __shfl_xor(mx, 32, 64));
      if (__any(mx - m_run[f] > 8.f)) {
        const float mnew = fmaxf(m_run[f], mx);
        const float sc = __builtin_amdgcn_exp2f(m_run[f] - mnew);
        m_run[f] = mnew;
        l_run[f] *= sc;
#pragma unroll
        for (int j = 0; j < 4; ++j)
#pragma unroll
          for (int r = 0; r < 4; ++r) acc[f][j][r] *= sc;
      }
      float ps = 0.f;
      bf16x4 pb[4];
#pragma unroll
      for (int kc = 0; kc < 4; ++kc)
#pragma unroll
        for (int r = 0; r < 4; ++r) {
          const float p = __builtin_amdgcn_exp2f(sv[kc * 4 + r] - m_run[f]);
          ps += p;
          pb[kc][r] = (bf16)p;
        }
      ps += __shfl_xor(ps, 16, 64);
      ps += __shfl_xor(ps, 32, 64);
      l_run[f] += ps;
#pragma unroll
      for (int kc = 0; kc < 4; ++kc)
        *(bf16x4*)&Pw[wid][lr * 76 + kc * 16 + hi2 * 4] = pb[kc];

      __builtin_amdgcn_s_setprio(1);
#pragma unroll
      for (int kk = 0; kk < 2; ++kk) {
        const bf16x8 ap = *(const bf16x8*)&Pw[wid][lr * 76 + kk * 32 + lk];
        const int kbase = kk * 4 + hi2;
#pragma unroll
        for (int j = 0; j < 4; ++j) {
          const int dv = j * 16 + lr;
          const bf16x8 bv = *(const bf16x8*)&Vtb[dv * 64 + ((kbase ^ (dv & 7)) << 3)];
          acc[f][j] = __builtin_amdgcn_mfma_f32_16x16x32_bf16(bv, ap, acc[f][j], 0, 0, 0);
        }
      }
      __builtin_amdgcn_s_setprio(0);
    }
    __builtin_amdgcn_s_barrier();
    __builtin_amdgcn_sched_barrier(0);
  }

#pragma unroll
  for (int f = 0; f < 2; ++f) {
    const int qv = q0 + f * 128 + wid * 16 + lr;
    const float linv = (l_run[f] > 0.f) ? 1.f / l_run[f] : 0.f;
#pragma unroll
    for (int j = 0; j < 4; ++j) {
      bf16x4 ov;
#pragma unroll
      for (int r = 0; r < 4; ++r) ov[r] = (bf16)(acc[f][j][r] * linv);
      *(bf16x4*)&O[(size_t)(b * NS + qv) * ND + h * 64 + j * 16 + hi2 * 4] = ov;
    }
  }
}

// ---------------- host ----------------
extern "C" void kernel_launch(void* const* d_in, const int* in_sizes, int n_in,
                              void* d_out, int out_size, void* d_ws, size_t ws_size,
                              hipStream_t stream) {
  const float* x = (const float*)d_in[0];
  const float* wq = (const float*)d_in[1];
  const float* bq = (const float*)d_in[2];
  const float* wk = (const float*)d_in[3];
  const float* bk = (const float*)d_in[4];
  const float* wv = (const float*)d_in[5];
  const float* bv = (const float*)d_in[6];
  const float* wfc = (const float*)d_in[7];
  const float* bfc = (const float*)d_in[8];
  const float* ln1g = (const float*)d_in[9];
  const float* ln1b = (const float*)d_in[10];
  const float* w1f = (const float*)d_in[11];
  const float* b1f = (const float*)d_in[12];
  const float* w2f = (const float*)d_in[13];
  const float* b2f = (const float*)d_in[14];
  const float* ln2g = (const float*)d_in[15];
  const float* ln2b = (const float*)d_in[16];
  const int* cur = (const int*)d_in[17];
  float* out = (float*)d_out;

  char* ws = (char*)d_ws;
  size_t off = 0;
  auto alloc = [&](size_t bytes) {
    void* p = ws + off;
    off += (bytes + 255) & ~(size_t)255;
    return p;
  };
  bf16* xb = (bf16*)alloc((size_t)NTOK * ND * 2);     // bf16 x (kept intact; gemm_ln resid)
  bf16* AO = (bf16*)alloc((size_t)NTOK * ND * 2);     // attention output
  bf16* w3b = (bf16*)alloc((size_t)3 * ND * ND * 2);  // [wq;wk;wv]
  bf16* wfcb = (bf16*)alloc((size_t)ND * ND * 2);
  bf16* w1fb = (bf16*)alloc((size_t)NDFF * ND * 2);
  bf16* w2fb = (bf16*)alloc((size_t)ND * NDFF * 2);
  float* b3 = (float*)alloc((size_t)3 * ND * 4);
  bf16* qkb = (bf16*)alloc((size_t)NTOK * LDK * 2);  // reused as ln1 bf16
  bf16* VTg = (bf16*)alloc((size_t)ND * NTOK * 2);   // V^T [512][16384]
  bf16* hb = (bf16*)alloc((size_t)NTOK * NDFF * 2);
  bf16* sum2 = (bf16*)alloc((size_t)NTOK * ND * 2);  // pre-LN2 sum (bf16)
  bf16* ln1bb = qkb;  // LN1 output bf16: FFN1 input AND FFN2 residual

  cvt_all<<<dim3(11264), dim3(256), 0, stream>>>(x, wq, wk, wv, wfc, w1f, w2f,
                                                 xb, w3b, wfcb, w1fb, w2fb);
  concat3<<<dim3(1), dim3(512), 0, stream>>>(bq, bk, bv, b3);

  // fused QKV projection: QK -> qkb (stride 1024), V -> VTg transposed
  gemm_bt<false, true, false><<<dim3(1536 / 128, NTOK / 256), dim3(512), 0, stream>>>(
      xb, w3b, b3, qkb, VTg, nullptr, NTOK, 1536, ND);
  // attention -> AO (QBLK=256, 8 waves, 2 q-frags/wave)
  attn_k<<<dim3(NB * NH, NS / 256), dim3(512), 0, stream>>>(qkb, VTg, AO, cur);
  // fc + resid(xb bf16) + LN1 -> ln1bb (bf16, single write)
  gemm_ln<<<dim3(NTOK / 64), dim3(512), 0, stream>>>(
      AO, wfcb, bfc, xb, ln1bb, ln1g, ln1b, 1e-5f, ND);
  // FFN1 + ReLU -> hb (bf16)
  gemm_bt<true, false, false><<<dim3(NDFF / 128, NTOK / 256), dim3(512), 0, stream>>>(
      ln1bb, w1fb, b1f, hb, nullptr, nullptr, NTOK, NDFF, ND);
  // FFN2 + resid(ln1 bf16) -> sum2 (bf16)
  gemm_bt<false, false, true><<<dim3(ND / 128, NTOK / 256), dim3(512), 0, stream>>>(
      hb, w2fb, b2f, sum2, nullptr, ln1bb, NTOK, ND, NDFF);
  // LN2: bf16 in -> fp32 out
  layernorm_b<<<dim3(NTOK / 4), dim3(256), 0, stream>>>(sum2, ln2g, ln2b, 1e-6f, out);
}

// Round 19
// 209.628 us; speedup vs baseline: 1.0132x; 1.0132x over previous
//
#include <hip/hip_runtime.h>
#include <hip/hip_bf16.h>
#include <stdint.h>
#include <stddef.h>

#define NB 16
#define NS 1024
#define ND 512
#define NH 8
#define NDFF 2048
#define NTOK (NB * NS)
#define LDK 1024  // fused QK row stride

typedef __bf16 bf16;
typedef __attribute__((ext_vector_type(2))) __bf16 bf16x2;
typedef __attribute__((ext_vector_type(4))) __bf16 bf16x4;
typedef __attribute__((ext_vector_type(8))) __bf16 bf16x8;
typedef __attribute__((ext_vector_type(4))) float f32x4;

__device__ __forceinline__ void async_copy16(const void* g, void* l) {
  __builtin_amdgcn_global_load_lds(
      (const __attribute__((address_space(1))) void*)g,
      (__attribute__((address_space(3))) void*)l,
      16, 0, 0);
}

// ---------------- all fp32 -> bf16 conversions in one kernel ----------------
__global__ __launch_bounds__(256) void cvt_all(
    const float* __restrict__ x, const float* __restrict__ wq,
    const float* __restrict__ wk, const float* __restrict__ wv,
    const float* __restrict__ wfc, const float* __restrict__ w1f,
    const float* __restrict__ w2f,
    bf16* __restrict__ xb, bf16* __restrict__ w3b,
    bf16* __restrict__ wfcb, bf16* __restrict__ w1fb, bf16* __restrict__ w2fb) {
  constexpr int C0 = 2097152, C1 = C0 + 65536, C2 = C1 + 65536, C3 = C2 + 65536,
                C4 = C3 + 65536, C5 = C4 + 262144;
  const int i = blockIdx.x * 256 + threadIdx.x;
  const float* s;
  bf16* d;
  int base;
  if (i < C0)      { s = x;   d = xb;            base = 0;  }
  else if (i < C1) { s = wq;  d = w3b;           base = C0; }
  else if (i < C2) { s = wk;  d = w3b + 262144;  base = C1; }
  else if (i < C3) { s = wv;  d = w3b + 524288;  base = C2; }
  else if (i < C4) { s = wfc; d = wfcb;          base = C3; }
  else if (i < C5) { s = w1f; d = w1fb;          base = C4; }
  else             { s = w2f; d = w2fb;          base = C5; }
  const int k = i - base;
  const float4 v = ((const float4*)s)[k];
  bf16x4 o = {(bf16)v.x, (bf16)v.y, (bf16)v.z, (bf16)v.w};
  ((bf16x4*)d)[k] = o;
}

// ---------------- concat 3 bias vectors (512 each) ----------------
__global__ __launch_bounds__(512) void concat3(const float* __restrict__ a,
                                               const float* __restrict__ b,
                                               const float* __restrict__ c,
                                               float* __restrict__ o) {
  const int t = threadIdx.x;
  o[t] = a[t];
  o[512 + t] = b[t];
  o[1024 + t] = c[t];
}

// LDS chunk swizzle: within a 16-row x 4-chunk (64B-row) segment, slot (r,c)
// holds global chunk c ^ ((r>>1)&3) (source-pre-swizzled, rule 21).
__device__ __forceinline__ int swz_src_col(int lane) {
  const int r = lane >> 2, c = lane & 3;
  return (c ^ ((r >> 1) & 3)) * 8;
}

// ---------------- GEMM 256x128, BK=32, 512 thr = 8 waves (4m x 2n), wave 64x64 ----
// Counted-vmcnt double-buffer schedule. XCD-swizzled (grids %8==0).
// QKV mode: N=1536; cols<512 (Q) scaled by SCL2; cols<1024 -> qkb (stride 1024);
//           cols>=1024 -> V^T to Cvt.
// RESB mode: bf16 out = acc + bias + bf16 residual (pre-LN2 sum).
template <bool RELU, bool QKV, bool RESB>
__global__ __launch_bounds__(512, 4) void gemm_bt(
    const bf16* __restrict__ A, const bf16* __restrict__ Bw,
    const float* __restrict__ bias, bf16* __restrict__ Cb,
    bf16* __restrict__ Cvt, const bf16* __restrict__ residb,
    int M, int N, int K) {
  __shared__ bf16 As[2][256 * 32];  // 16 KB per buffer
  __shared__ bf16 Bs[2][128 * 32];  // 8 KB per buffer
  const int tid = threadIdx.x;
  const int lane = tid & 63;
  const int wid = tid >> 6;  // 0..7

  const int nwg = gridDim.x * gridDim.y;
  int id = blockIdx.y * gridDim.x + blockIdx.x;
  id = (id & 7) * (nwg >> 3) + (id >> 3);
  const int tn = id % gridDim.x, tm = id / gridDim.x;

  const int wm = wid >> 1, wn = wid & 1;  // wave tile: rows wm*64, cols wn*64
  const int lr = lane & 15, hi2 = lane >> 4;
  const int lkA = ((hi2 ^ ((lr >> 1) & 3)) << 3);  // swizzled read chunk
  const int srow = lane >> 2, scol = swz_src_col(lane);

  f32x4 acc[4][4] = {};

  const bf16* Abase = A + (size_t)(tm * 256 + srow) * K + scol;
  const bf16* Bbase = Bw + (size_t)(tn * 128 + srow) * K + scol;
  const int kiters = K >> 5;

  // 24 chunk-copies (16 A segs + 8 B segs), 3 per wave
  auto stage = [&](int buf, int kb) {
#pragma unroll
    for (int t = 0; t < 3; ++t) {
      const int c = wid * 3 + t;
      if (c < 16) {
        async_copy16(Abase + (size_t)c * 16 * K + kb * 32, &As[buf][c * 512]);
      } else {
        const int s = c - 16;
        async_copy16(Bbase + (size_t)s * 16 * K + kb * 32, &Bs[buf][s * 512]);
      }
    }
  };

  stage(0, 0);

  int buf = 0;
  for (int kb = 0; kb < kiters; ++kb) {
    if (kb + 1 < kiters) {
      stage(buf ^ 1, kb + 1);
      asm volatile("s_waitcnt vmcnt(3)" ::: "memory");  // wait prev tile only
    } else {
      asm volatile("s_waitcnt vmcnt(0)" ::: "memory");
    }
    __builtin_amdgcn_s_barrier();
    __builtin_amdgcn_sched_barrier(0);

    bf16x8 af[4], bfr[4];
#pragma unroll
    for (int i = 0; i < 4; ++i)
      af[i] = *(const bf16x8*)&As[buf][(wm * 64 + i * 16 + lr) * 32 + lkA];
#pragma unroll
    for (int j = 0; j < 4; ++j)
      bfr[j] = *(const bf16x8*)&Bs[buf][(wn * 64 + j * 16 + lr) * 32 + lkA];
#pragma unroll
    for (int i = 0; i < 4; ++i)
#pragma unroll
      for (int j = 0; j < 4; ++j)
        acc[i][j] = __builtin_amdgcn_mfma_f32_16x16x32_bf16(af[i], bfr[j], acc[i][j], 0, 0, 0);

    __builtin_amdgcn_s_barrier();
    __builtin_amdgcn_sched_barrier(0);
    buf ^= 1;
  }

  const float SCL2 = 0.18033688f;  // (1/sqrt(64)) * log2(e) folded into Q
#pragma unroll
  for (int i = 0; i < 4; ++i) {
    const int row0 = tm * 256 + wm * 64 + i * 16 + hi2 * 4;
#pragma unroll
    for (int j = 0; j < 4; ++j) {
      const int col = tn * 128 + wn * 64 + j * 16 + lr;
      const float bcol = bias[col];
      if (QKV && col >= 1024) {
        bf16x4 ov;
#pragma unroll
        for (int r = 0; r < 4; ++r) ov[r] = (bf16)(acc[i][j][r] + bcol);
        *(bf16x4*)&Cvt[(size_t)(col - 1024) * M + row0] = ov;
      } else if (RESB) {
#pragma unroll
        for (int r = 0; r < 4; ++r) {
          const size_t idx = (size_t)(row0 + r) * N + col;
          Cb[idx] = (bf16)(acc[i][j][r] + bcol + (float)residb[idx]);
        }
      } else {
        const int strideN = QKV ? 1024 : N;
#pragma unroll
        for (int r = 0; r < 4; ++r) {
          float c = acc[i][j][r] + bcol;
          if (QKV && col < 512) c *= SCL2;  // pre-scale Q for log2-domain softmax
          if (RELU) c = fmaxf(c, 0.f);
          Cb[(size_t)(row0 + r) * strideN + col] = (bf16)c;
        }
      }
    }
  }
}

// ---------------- GEMM (BM=64, BN=N=512) + bias + bf16 resid + fused LayerNorm ----------------
// K=512 only (fc+LN1). Writes LN output ONCE as bf16 (FFN1 input AND FFN2 resid).
__global__ __launch_bounds__(512) void gemm_ln(
    const bf16* __restrict__ A, const bf16* __restrict__ Bw,
    const float* __restrict__ bias, const bf16* __restrict__ resid,
    bf16* __restrict__ outB,
    const float* __restrict__ gam, const float* __restrict__ bet,
    float eps, int K) {
  __shared__ bf16 As[2][64 * 32];
  __shared__ bf16 Bs[2][512 * 32];
  __shared__ float red[8 * 32 * 2];
  const int tid = threadIdx.x;
  const int lane = tid & 63;
  const int wid = tid >> 6;
  const int wm = wid >> 2, wn = wid & 3;
  const int lr = lane & 15, hi2 = lane >> 4;
  const int lkA = ((hi2 ^ ((lr >> 1) & 3)) << 3);
  const int tm = blockIdx.x;

  f32x4 acc[2][8] = {};
  const int kiters = K >> 5;
  const int r4 = lane >> 2, c4 = swz_src_col(lane);

  auto stage = [&](int buf, int kb) {
    if (wid < 4) {
      async_copy16(A + (size_t)(tm * 64 + wid * 16 + r4) * K + kb * 32 + c4,
                   &As[buf][wid * 16 * 32]);
#pragma unroll
      for (int i = 0; i < 3; ++i) {
        const int s = wid * 3 + i;
        async_copy16(Bw + (size_t)(s * 16 + r4) * K + kb * 32 + c4, &Bs[buf][s * 16 * 32]);
      }
    } else {
#pragma unroll
      for (int i = 0; i < 5; ++i) {
        const int s = 12 + (wid - 4) * 5 + i;
        async_copy16(Bw + (size_t)(s * 16 + r4) * K + kb * 32 + c4, &Bs[buf][s * 16 * 32]);
      }
    }
  };

  stage(0, 0);

  int buf = 0;
  for (int kb = 0; kb < kiters; ++kb) {
    if (kb + 1 < kiters) {
      stage(buf ^ 1, kb + 1);
      if (wid < 4) asm volatile("s_waitcnt vmcnt(4)" ::: "memory");
      else         asm volatile("s_waitcnt vmcnt(5)" ::: "memory");
    } else {
      asm volatile("s_waitcnt vmcnt(0)" ::: "memory");
    }
    __builtin_amdgcn_s_barrier();
    __builtin_amdgcn_sched_barrier(0);

    bf16x8 af[2], bfr[8];
#pragma unroll
    for (int i = 0; i < 2; ++i)
      af[i] = *(const bf16x8*)&As[buf][(wm * 32 + i * 16 + lr) * 32 + lkA];
#pragma unroll
    for (int j = 0; j < 8; ++j)
      bfr[j] = *(const bf16x8*)&Bs[buf][(wn * 128 + j * 16 + lr) * 32 + lkA];
#pragma unroll
    for (int i = 0; i < 2; ++i)
#pragma unroll
      for (int j = 0; j < 8; ++j)
        acc[i][j] = __builtin_amdgcn_mfma_f32_16x16x32_bf16(af[i], bfr[j], acc[i][j], 0, 0, 0);

    __builtin_amdgcn_s_barrier();
    __builtin_amdgcn_sched_barrier(0);
    buf ^= 1;
  }

  float bi[8];
#pragma unroll
  for (int j = 0; j < 8; ++j) bi[j] = bias[wn * 128 + j * 16 + lr];
#pragma unroll
  for (int i = 0; i < 2; ++i)
#pragma unroll
    for (int r = 0; r < 4; ++r) {
      const int rowg = tm * 64 + wm * 32 + i * 16 + hi2 * 4 + r;
#pragma unroll
      for (int j = 0; j < 8; ++j)
        acc[i][j][r] += bi[j] + (float)resid[(size_t)rowg * ND + wn * 128 + j * 16 + lr];
    }
#pragma unroll
  for (int i = 0; i < 2; ++i)
#pragma unroll
    for (int r = 0; r < 4; ++r) {
      float s = 0.f, s2 = 0.f;
#pragma unroll
      for (int j = 0; j < 8; ++j) {
        const float v = acc[i][j][r];
        s += v;
        s2 += v * v;
      }
#pragma unroll
      for (int o = 1; o < 16; o <<= 1) {
        s += __shfl_xor(s, o, 64);
        s2 += __shfl_xor(s2, o, 64);
      }
      if (lr == 0) {
        red[(wid * 32 + i * 16 + hi2 * 4 + r) * 2 + 0] = s;
        red[(wid * 32 + i * 16 + hi2 * 4 + r) * 2 + 1] = s2;
      }
    }
  __syncthreads();
  float g8[8], be8[8];
#pragma unroll
  for (int j = 0; j < 8; ++j) {
    g8[j] = gam[wn * 128 + j * 16 + lr];
    be8[j] = bet[wn * 128 + j * 16 + lr];
  }
#pragma unroll
  for (int i = 0; i < 2; ++i)
#pragma unroll
    for (int r = 0; r < 4; ++r) {
      const int rlw = i * 16 + hi2 * 4 + r;
      float S = 0.f, S2 = 0.f;
#pragma unroll
      for (int q = 0; q < 4; ++q) {
        S += red[((wm * 4 + q) * 32 + rlw) * 2 + 0];
        S2 += red[((wm * 4 + q) * 32 + rlw) * 2 + 1];
      }
      const float mu = S * (1.f / ND);
      const float rstd = rsqrtf(S2 * (1.f / ND) - mu * mu + eps);
      const int rowg = tm * 64 + wm * 32 + rlw;
#pragma unroll
      for (int j = 0; j < 8; ++j) {
        const float ln = (acc[i][j][r] - mu) * rstd * g8[j] + be8[j];
        outB[(size_t)rowg * ND + wn * 128 + j * 16 + lr] = (bf16)ln;
      }
    }
}

// ---------------- LayerNorm: bf16 in -> fp32 out, one wave per row of 512 ----------------
__global__ __launch_bounds__(256) void layernorm_b(
    const bf16* __restrict__ in, const float* __restrict__ gam,
    const float* __restrict__ bet, float eps, float* __restrict__ outf) {
  const int row = blockIdx.x * 4 + (threadIdx.x >> 6);
  const int lane = threadIdx.x & 63;
  const bf16x8 v = ((const bf16x8*)(in + (size_t)row * ND))[lane];
  float f[8];
  float s = 0.f, s2 = 0.f;
#pragma unroll
  for (int e = 0; e < 8; ++e) {
    f[e] = (float)v[e];
    s += f[e];
    s2 += f[e] * f[e];
  }
#pragma unroll
  for (int off = 1; off < 64; off <<= 1) {
    s += __shfl_xor(s, off, 64);
    s2 += __shfl_xor(s2, off, 64);
  }
  const float mu = s * (1.f / ND);
  const float var = s2 * (1.f / ND) - mu * mu;
  const float rstd = rsqrtf(var + eps);
  const float4 g0 = ((const float4*)gam)[lane * 2];
  const float4 g1 = ((const float4*)gam)[lane * 2 + 1];
  const float4 b0 = ((const float4*)bet)[lane * 2];
  const float4 b1 = ((const float4*)bet)[lane * 2 + 1];
  float4 o0, o1;
  o0.x = (f[0] - mu) * rstd * g0.x + b0.x;
  o0.y = (f[1] - mu) * rstd * g0.y + b0.y;
  o0.z = (f[2] - mu) * rstd * g0.z + b0.z;
  o0.w = (f[3] - mu) * rstd * g0.w + b0.w;
  o1.x = (f[4] - mu) * rstd * g1.x + b1.x;
  o1.y = (f[5] - mu) * rstd * g1.y + b1.y;
  o1.z = (f[6] - mu) * rstd * g1.z + b1.z;
  o1.w = (f[7] - mu) * rstd * g1.w + b1.w;
  float* op = outf + (size_t)row * ND;
  ((float4*)op)[lane * 2] = o0;
  ((float4*)op)[lane * 2 + 1] = o1;
}

// ---------------- Flash attention, causal diag -current (r17 best config) ----------------
// QBLK=128: 512 thr = 8 waves, wave w owns q rows [q0+16w, +16). K/V staged once
// per 128 q (1 K-copy + 1 V-copy per wave, vmcnt(2)). Heavy q-blocks first.
// Q pre-scaled by SCL2 at projection -> scores already log2-domain.
// Pw stride 76 bf16: bank advance 6/row -> <=2-way (free) on P path.
__global__ __launch_bounds__(512) void attn_k(
    const bf16* __restrict__ QKg, const bf16* __restrict__ VTg,
    bf16* __restrict__ O, const int* __restrict__ curp) {
  const int current = *curp;
  const int bh = blockIdx.x;
  const int b = bh >> 3, h = bh & 7;
  const int q0 = (gridDim.y - 1 - blockIdx.y) * 128;  // heavy-first dispatch
  const int tid = threadIdx.x, lane = tid & 63, wid = tid >> 6;  // wid 0..7
  const int lr = lane & 15, hi2 = lane >> 4, lk = hi2 * 8;

  __shared__ bf16 Kt[2][64 * 64];
  __shared__ bf16 Vt2[2][64 * 64];
  __shared__ bf16 Pw[8][16 * 76];

  const size_t qoff = (size_t)(b * NS + q0 + wid * 16 + lr) * LDK + h * 64 + lk;
  const bf16x8 aq0 = *(const bf16x8*)&QKg[qoff];
  const bf16x8 aq1 = *(const bf16x8*)&QKg[qoff + 32];

  f32x4 acc[4] = {};
  float m_run = -1e30f, l_run = 0.f;

  int kmax = q0 + 127 - current;
  if (kmax > NS - 1) kmax = NS - 1;
  const int nkt = (kmax >= 0) ? ((kmax >> 6) + 1) : 0;
  const int qv = q0 + wid * 16 + lr;

  const int kchunk = (lane & 7) ^ (lane >> 3);  // K source pre-swizzle
  const int vdv = wid * 8 + (lane >> 3);        // V dest dv row
  const int vkeyc = ((lane & 7) ^ (lane >> 3)) * 8;  // V source key chunk (swz)

  auto stageKV = [&](int kt_, int buf_) {
    const int k0_ = kt_ * 64;
    const int rloc = wid * 8 + (lane >> 3);
    async_copy16(&QKg[(size_t)(b * NS + k0_ + rloc) * LDK + 512 + h * 64 + kchunk * 8],
                 &Kt[buf_][wid * 512]);
    async_copy16(&VTg[(size_t)(h * 64 + vdv) * NTOK + b * NS + k0_ + vkeyc],
                 &Vt2[buf_][wid * 512]);
  };

  if (nkt > 0) stageKV(0, 0);

  for (int kt = 0; kt < nkt; ++kt) {
    const int buf = kt & 1;
    if (kt + 1 < nkt) {
      stageKV(kt + 1, buf ^ 1);
      asm volatile("s_waitcnt vmcnt(2)" ::: "memory");
    } else {
      asm volatile("s_waitcnt vmcnt(0)" ::: "memory");
    }
    __builtin_amdgcn_s_barrier();
    __builtin_amdgcn_sched_barrier(0);

    const int k0 = kt * 64;
    const bf16* Ktb = &Kt[buf][0];
    const bf16* Vtb = &Vt2[buf][0];

    f32x4 sf[4];
    __builtin_amdgcn_s_setprio(1);
#pragma unroll
    for (int kc = 0; kc < 4; ++kc) {
      const int row = kc * 16 + lr;
      const int idx0 = row * 64 + ((hi2 ^ (lr & 7)) << 3);
      f32x4 z = {};
      const bf16x8 bk0 = *(const bf16x8*)&Ktb[idx0];
      const bf16x8 bk1 = *(const bf16x8*)&Ktb[idx0 ^ 32];
      z = __builtin_amdgcn_mfma_f32_16x16x32_bf16(bk0, aq0, z, 0, 0, 0);
      z = __builtin_amdgcn_mfma_f32_16x16x32_bf16(bk1, aq1, z, 0, 0, 0);
      sf[kc] = z;  // already log2-domain (SCL2 folded into Q at projection)
    }
    __builtin_amdgcn_s_setprio(0);

    float sv[16];
    float mx = -1e30f;
    const bool full = (k0 + 63 + current <= q0 + wid * 16);
    if (full) {
#pragma unroll
      for (int kc = 0; kc < 4; ++kc)
#pragma unroll
        for (int r = 0; r < 4; ++r) {
          const float s = sf[kc][r];
          sv[kc * 4 + r] = s;
          mx = fmaxf(mx, s);
        }
    } else {
      const int keyb = k0 + hi2 * 4;
#pragma unroll
      for (int kc = 0; kc < 4; ++kc)
#pragma unroll
        for (int r = 0; r < 4; ++r) {
          const int key = keyb + kc * 16 + r;
          const float s = (key + current <= qv) ? sf[kc][r] : -3.0e38f;
          sv[kc * 4 + r] = s;
          mx = fmaxf(mx, s);
        }
    }
    mx = fmaxf(mx, __shfl_xor(mx, 16, 64));
    mx = fmaxf(mx, __shfl_xor(mx, 32, 64));
    if (__any(mx - m_run > 8.f)) {
      const float mnew = fmaxf(m_run, mx);
      const float sc = __builtin_amdgcn_exp2f(m_run - mnew);
      m_run = mnew;
      l_run *= sc;
#pragma unroll
      for (int j = 0; j < 4; ++j)
#pragma unroll
        for (int r = 0; r < 4; ++r) acc[j][r] *= sc;
    }
    float ps = 0.f;
    bf16x4 pb[4];
#pragma unroll
    for (int kc = 0; kc < 4; ++kc)
#pragma unroll
      for (int r = 0; r < 4; ++r) {
        const float p = __builtin_amdgcn_exp2f(sv[kc * 4 + r] - m_run);
        ps += p;
        pb[kc][r] = (bf16)p;
      }
    ps += __shfl_xor(ps, 16, 64);
    ps += __shfl_xor(ps, 32, 64);
    l_run += ps;
#pragma unroll
    for (int kc = 0; kc < 4; ++kc)
      *(bf16x4*)&Pw[wid][lr * 76 + kc * 16 + hi2 * 4] = pb[kc];

    __builtin_amdgcn_s_setprio(1);
#pragma unroll
    for (int kk = 0; kk < 2; ++kk) {
      const bf16x8 ap = *(const bf16x8*)&Pw[wid][lr * 76 + kk * 32 + lk];
      const int kbase = kk * 4 + hi2;
#pragma unroll
      for (int j = 0; j < 4; ++j) {
        const int dv = j * 16 + lr;
        const bf16x8 bv = *(const bf16x8*)&Vtb[dv * 64 + ((kbase ^ (dv & 7)) << 3)];
        acc[j] = __builtin_amdgcn_mfma_f32_16x16x32_bf16(bv, ap, acc[j], 0, 0, 0);
      }
    }
    __builtin_amdgcn_s_setprio(0);
    __builtin_amdgcn_s_barrier();
    __builtin_amdgcn_sched_barrier(0);
  }

  const float linv = (l_run > 0.f) ? 1.f / l_run : 0.f;
#pragma unroll
  for (int j = 0; j < 4; ++j) {
    bf16x4 ov;
#pragma unroll
    for (int r = 0; r < 4; ++r) ov[r] = (bf16)(acc[j][r] * linv);
    *(bf16x4*)&O[(size_t)(b * NS + qv) * ND + h * 64 + j * 16 + hi2 * 4] = ov;
  }
}

// ---------------- host ----------------
extern "C" void kernel_launch(void* const* d_in, const int* in_sizes, int n_in,
                              void* d_out, int out_size, void* d_ws, size_t ws_size,
                              hipStream_t stream) {
  const float* x = (const float*)d_in[0];
  const float* wq = (const float*)d_in[1];
  const float* bq = (const float*)d_in[2];
  const float* wk = (const float*)d_in[3];
  const float* bk = (const float*)d_in[4];
  const float* wv = (const float*)d_in[5];
  const float* bv = (const float*)d_in[6];
  const float* wfc = (const float*)d_in[7];
  const float* bfc = (const float*)d_in[8];
  const float* ln1g = (const float*)d_in[9];
  const float* ln1b = (const float*)d_in[10];
  const float* w1f = (const float*)d_in[11];
  const float* b1f = (const float*)d_in[12];
  const float* w2f = (const float*)d_in[13];
  const float* b2f = (const float*)d_in[14];
  const float* ln2g = (const float*)d_in[15];
  const float* ln2b = (const float*)d_in[16];
  const int* cur = (const int*)d_in[17];
  float* out = (float*)d_out;

  char* ws = (char*)d_ws;
  size_t off = 0;
  auto alloc = [&](size_t bytes) {
    void* p = ws + off;
    off += (bytes + 255) & ~(size_t)255;
    return p;
  };
  bf16* xb = (bf16*)alloc((size_t)NTOK * ND * 2);     // bf16 x (kept intact; gemm_ln resid)
  bf16* AO = (bf16*)alloc((size_t)NTOK * ND * 2);     // attention output
  bf16* w3b = (bf16*)alloc((size_t)3 * ND * ND * 2);  // [wq;wk;wv]
  bf16* wfcb = (bf16*)alloc((size_t)ND * ND * 2);
  bf16* w1fb = (bf16*)alloc((size_t)NDFF * ND * 2);
  bf16* w2fb = (bf16*)alloc((size_t)ND * NDFF * 2);
  float* b3 = (float*)alloc((size_t)3 * ND * 4);
  bf16* qkb = (bf16*)alloc((size_t)NTOK * LDK * 2);  // reused as ln1 bf16
  bf16* VTg = (bf16*)alloc((size_t)ND * NTOK * 2);   // V^T [512][16384]
  bf16* hb = (bf16*)alloc((size_t)NTOK * NDFF * 2);
  bf16* sum2 = (bf16*)alloc((size_t)NTOK * ND * 2);  // pre-LN2 sum (bf16)
  bf16* ln1bb = qkb;  // LN1 output bf16: FFN1 input AND FFN2 residual

  cvt_all<<<dim3(11264), dim3(256), 0, stream>>>(x, wq, wk, wv, wfc, w1f, w2f,
                                                 xb, w3b, wfcb, w1fb, w2fb);
  concat3<<<dim3(1), dim3(512), 0, stream>>>(bq, bk, bv, b3);

  // fused QKV projection: QK -> qkb (stride 1024, Q pre-scaled), V -> VTg transposed
  gemm_bt<false, true, false><<<dim3(1536 / 128, NTOK / 256), dim3(512), 0, stream>>>(
      xb, w3b, b3, qkb, VTg, nullptr, NTOK, 1536, ND);
  // attention -> AO (QBLK=128, 8 waves)
  attn_k<<<dim3(NB * NH, NS / 128), dim3(512), 0, stream>>>(qkb, VTg, AO, cur);
  // fc + resid(xb bf16) + LN1 -> ln1bb (bf16, single write)
  gemm_ln<<<dim3(NTOK / 64), dim3(512), 0, stream>>>(
      AO, wfcb, bfc, xb, ln1bb, ln1g, ln1b, 1e-5f, ND);
  // FFN1 + ReLU -> hb (bf16)
  gemm_bt<true, false, false><<<dim3(NDFF / 128, NTOK / 256), dim3(512), 0, stream>>>(
      ln1bb, w1fb, b1f, hb, nullptr, nullptr, NTOK, NDFF, ND);
  // FFN2 + resid(ln1 bf16) -> sum2 (bf16)
  gemm_bt<false, false, true><<<dim3(ND / 128, NTOK / 256), dim3(512), 0, stream>>>(
      hb, w2fb, b2f, sum2, nullptr, ln1bb, NTOK, ND, NDFF);
  // LN2: bf16 in -> fp32 out
  layernorm_b<<<dim3(NTOK / 4), dim3(256), 0, stream>>>(sum2, ln2g, ln2b, 1e-6f, out);
}

// Round 20
// 207.162 us; speedup vs baseline: 1.0252x; 1.0119x over previous
//
#include <hip/hip_runtime.h>
#include <hip/hip_bf16.h>
#include <stdint.h>
#include <stddef.h>

#define NB 16
#define NS 1024
#define ND 512
#define NH 8
#define NDFF 2048
#define NTOK (NB * NS)
#define LDK 1024  // fused QK row stride

typedef __bf16 bf16;
typedef __attribute__((ext_vector_type(2))) __bf16 bf16x2;
typedef __attribute__((ext_vector_type(4))) __bf16 bf16x4;
typedef __attribute__((ext_vector_type(8))) __bf16 bf16x8;
typedef __attribute__((ext_vector_type(4))) float f32x4;

__device__ __forceinline__ void async_copy16(const void* g, void* l) {
  __builtin_amdgcn_global_load_lds(
      (const __attribute__((address_space(1))) void*)g,
      (__attribute__((address_space(3))) void*)l,
      16, 0, 0);
}

// ---------------- all fp32 -> bf16 conversions in one kernel ----------------
__global__ __launch_bounds__(256) void cvt_all(
    const float* __restrict__ x, const float* __restrict__ wq,
    const float* __restrict__ wk, const float* __restrict__ wv,
    const float* __restrict__ wfc, const float* __restrict__ w1f,
    const float* __restrict__ w2f,
    bf16* __restrict__ xb, bf16* __restrict__ w3b,
    bf16* __restrict__ wfcb, bf16* __restrict__ w1fb, bf16* __restrict__ w2fb) {
  constexpr int C0 = 2097152, C1 = C0 + 65536, C2 = C1 + 65536, C3 = C2 + 65536,
                C4 = C3 + 65536, C5 = C4 + 262144;
  const int i = blockIdx.x * 256 + threadIdx.x;
  const float* s;
  bf16* d;
  int base;
  if (i < C0)      { s = x;   d = xb;            base = 0;  }
  else if (i < C1) { s = wq;  d = w3b;           base = C0; }
  else if (i < C2) { s = wk;  d = w3b + 262144;  base = C1; }
  else if (i < C3) { s = wv;  d = w3b + 524288;  base = C2; }
  else if (i < C4) { s = wfc; d = wfcb;          base = C3; }
  else if (i < C5) { s = w1f; d = w1fb;          base = C4; }
  else             { s = w2f; d = w2fb;          base = C5; }
  const int k = i - base;
  const float4 v = ((const float4*)s)[k];
  bf16x4 o = {(bf16)v.x, (bf16)v.y, (bf16)v.z, (bf16)v.w};
  ((bf16x4*)d)[k] = o;
}

// ---------------- concat 3 bias vectors (512 each) ----------------
__global__ __launch_bounds__(512) void concat3(const float* __restrict__ a,
                                               const float* __restrict__ b,
                                               const float* __restrict__ c,
                                               float* __restrict__ o) {
  const int t = threadIdx.x;
  o[t] = a[t];
  o[512 + t] = b[t];
  o[1024 + t] = c[t];
}

// LDS chunk swizzle: within a 16-row x 4-chunk (64B-row) segment, slot (r,c)
// holds global chunk c ^ ((r>>1)&3) (source-pre-swizzled, rule 21).
__device__ __forceinline__ int swz_src_col(int lane) {
  const int r = lane >> 2, c = lane & 3;
  return (c ^ ((r >> 1) & 3)) * 8;
}

// ---------------- GEMM 256x128, BK=32, 512 thr = 8 waves, wave 64x64 ----------------
// Ring-of-3 LDS (72 KB), ONE barrier per K-step: vmcnt(3) -> barrier ->
// issue stage(t+2) -> ds_read+MFMA. 2 blocks/CU (same as 2-buffer config).
// QKV mode: N=1536; cols<512 (Q) scaled by SCL2; cols<1024 -> qkb (stride 1024);
//           cols>=1024 -> V^T to Cvt.
// RESB mode: bf16 out = acc + bias + bf16 residual (pre-LN2 sum).
template <bool RELU, bool QKV, bool RESB>
__global__ __launch_bounds__(512, 4) void gemm_bt(
    const bf16* __restrict__ A, const bf16* __restrict__ Bw,
    const float* __restrict__ bias, bf16* __restrict__ Cb,
    bf16* __restrict__ Cvt, const bf16* __restrict__ residb,
    int M, int N, int K) {
  __shared__ bf16 As[3][256 * 32];  // 16 KB per buffer
  __shared__ bf16 Bs[3][128 * 32];  // 8 KB per buffer
  const int tid = threadIdx.x;
  const int lane = tid & 63;
  const int wid = tid >> 6;  // 0..7

  const int nwg = gridDim.x * gridDim.y;
  int id = blockIdx.y * gridDim.x + blockIdx.x;
  id = (id & 7) * (nwg >> 3) + (id >> 3);
  const int tn = id % gridDim.x, tm = id / gridDim.x;

  const int wm = wid >> 1, wn = wid & 1;  // wave tile: rows wm*64, cols wn*64
  const int lr = lane & 15, hi2 = lane >> 4;
  const int lkA = ((hi2 ^ ((lr >> 1) & 3)) << 3);  // swizzled read chunk
  const int srow = lane >> 2, scol = swz_src_col(lane);

  f32x4 acc[4][4] = {};

  const bf16* Abase = A + (size_t)(tm * 256 + srow) * K + scol;
  const bf16* Bbase = Bw + (size_t)(tn * 128 + srow) * K + scol;
  const int kiters = K >> 5;

  // 24 chunk-copies (16 A segs + 8 B segs), 3 per wave
  auto stage = [&](int buf, int kb) {
#pragma unroll
    for (int t = 0; t < 3; ++t) {
      const int c = wid * 3 + t;
      if (c < 16) {
        async_copy16(Abase + (size_t)c * 16 * K + kb * 32, &As[buf][c * 512]);
      } else {
        const int s = c - 16;
        async_copy16(Bbase + (size_t)s * 16 * K + kb * 32, &Bs[buf][s * 512]);
      }
    }
  };

  stage(0, 0);
  stage(1, 1);

  int rbuf = 0;  // buffer holding tile kb
  int sbuf = 2;  // buffer to stage tile kb+2 into
  for (int kb = 0; kb < kiters; ++kb) {
    if (kb + 1 < kiters) {
      asm volatile("s_waitcnt vmcnt(3)" ::: "memory");  // tile kb landed; kb+1 in flight
    } else {
      asm volatile("s_waitcnt vmcnt(0)" ::: "memory");
    }
    __builtin_amdgcn_s_barrier();
    __builtin_amdgcn_sched_barrier(0);

    if (kb + 2 < kiters) stage(sbuf, kb + 2);  // flies under this step's MFMAs

    bf16x8 af[4], bfr[4];
#pragma unroll
    for (int i = 0; i < 4; ++i)
      af[i] = *(const bf16x8*)&As[rbuf][(wm * 64 + i * 16 + lr) * 32 + lkA];
#pragma unroll
    for (int j = 0; j < 4; ++j)
      bfr[j] = *(const bf16x8*)&Bs[rbuf][(wn * 64 + j * 16 + lr) * 32 + lkA];
#pragma unroll
    for (int i = 0; i < 4; ++i)
#pragma unroll
      for (int j = 0; j < 4; ++j)
        acc[i][j] = __builtin_amdgcn_mfma_f32_16x16x32_bf16(af[i], bfr[j], acc[i][j], 0, 0, 0);

    rbuf = (rbuf == 2) ? 0 : rbuf + 1;
    sbuf = (sbuf == 2) ? 0 : sbuf + 1;
  }

  const float SCL2 = 0.18033688f;  // (1/sqrt(64)) * log2(e) folded into Q
#pragma unroll
  for (int i = 0; i < 4; ++i) {
    const int row0 = tm * 256 + wm * 64 + i * 16 + hi2 * 4;
#pragma unroll
    for (int j = 0; j < 4; ++j) {
      const int col = tn * 128 + wn * 64 + j * 16 + lr;
      const float bcol = bias[col];
      if (QKV && col >= 1024) {
        bf16x4 ov;
#pragma unroll
        for (int r = 0; r < 4; ++r) ov[r] = (bf16)(acc[i][j][r] + bcol);
        *(bf16x4*)&Cvt[(size_t)(col - 1024) * M + row0] = ov;
      } else if (RESB) {
#pragma unroll
        for (int r = 0; r < 4; ++r) {
          const size_t idx = (size_t)(row0 + r) * N + col;
          Cb[idx] = (bf16)(acc[i][j][r] + bcol + (float)residb[idx]);
        }
      } else {
        const int strideN = QKV ? 1024 : N;
#pragma unroll
        for (int r = 0; r < 4; ++r) {
          float c = acc[i][j][r] + bcol;
          if (QKV && col < 512) c *= SCL2;  // pre-scale Q for log2-domain softmax
          if (RELU) c = fmaxf(c, 0.f);
          Cb[(size_t)(row0 + r) * strideN + col] = (bf16)c;
        }
      }
    }
  }
}

// ---------------- GEMM (BM=64, BN=N=512) + bias + bf16 resid + fused LayerNorm ----------------
// K=512 only (fc+LN1). Writes LN output ONCE as bf16 (FFN1 input AND FFN2 resid).
__global__ __launch_bounds__(512) void gemm_ln(
    const bf16* __restrict__ A, const bf16* __restrict__ Bw,
    const float* __restrict__ bias, const bf16* __restrict__ resid,
    bf16* __restrict__ outB,
    const float* __restrict__ gam, const float* __restrict__ bet,
    float eps, int K) {
  __shared__ bf16 As[2][64 * 32];
  __shared__ bf16 Bs[2][512 * 32];
  __shared__ float red[8 * 32 * 2];
  const int tid = threadIdx.x;
  const int lane = tid & 63;
  const int wid = tid >> 6;
  const int wm = wid >> 2, wn = wid & 3;
  const int lr = lane & 15, hi2 = lane >> 4;
  const int lkA = ((hi2 ^ ((lr >> 1) & 3)) << 3);
  const int tm = blockIdx.x;

  f32x4 acc[2][8] = {};
  const int kiters = K >> 5;
  const int r4 = lane >> 2, c4 = swz_src_col(lane);

  auto stage = [&](int buf, int kb) {
    if (wid < 4) {
      async_copy16(A + (size_t)(tm * 64 + wid * 16 + r4) * K + kb * 32 + c4,
                   &As[buf][wid * 16 * 32]);
#pragma unroll
      for (int i = 0; i < 3; ++i) {
        const int s = wid * 3 + i;
        async_copy16(Bw + (size_t)(s * 16 + r4) * K + kb * 32 + c4, &Bs[buf][s * 16 * 32]);
      }
    } else {
#pragma unroll
      for (int i = 0; i < 5; ++i) {
        const int s = 12 + (wid - 4) * 5 + i;
        async_copy16(Bw + (size_t)(s * 16 + r4) * K + kb * 32 + c4, &Bs[buf][s * 16 * 32]);
      }
    }
  };

  stage(0, 0);

  int buf = 0;
  for (int kb = 0; kb < kiters; ++kb) {
    if (kb + 1 < kiters) {
      stage(buf ^ 1, kb + 1);
      if (wid < 4) asm volatile("s_waitcnt vmcnt(4)" ::: "memory");
      else         asm volatile("s_waitcnt vmcnt(5)" ::: "memory");
    } else {
      asm volatile("s_waitcnt vmcnt(0)" ::: "memory");
    }
    __builtin_amdgcn_s_barrier();
    __builtin_amdgcn_sched_barrier(0);

    bf16x8 af[2], bfr[8];
#pragma unroll
    for (int i = 0; i < 2; ++i)
      af[i] = *(const bf16x8*)&As[buf][(wm * 32 + i * 16 + lr) * 32 + lkA];
#pragma unroll
    for (int j = 0; j < 8; ++j)
      bfr[j] = *(const bf16x8*)&Bs[buf][(wn * 128 + j * 16 + lr) * 32 + lkA];
#pragma unroll
    for (int i = 0; i < 2; ++i)
#pragma unroll
      for (int j = 0; j < 8; ++j)
        acc[i][j] = __builtin_amdgcn_mfma_f32_16x16x32_bf16(af[i], bfr[j], acc[i][j], 0, 0, 0);

    __builtin_amdgcn_s_barrier();
    __builtin_amdgcn_sched_barrier(0);
    buf ^= 1;
  }

  float bi[8];
#pragma unroll
  for (int j = 0; j < 8; ++j) bi[j] = bias[wn * 128 + j * 16 + lr];
#pragma unroll
  for (int i = 0; i < 2; ++i)
#pragma unroll
    for (int r = 0; r < 4; ++r) {
      const int rowg = tm * 64 + wm * 32 + i * 16 + hi2 * 4 + r;
#pragma unroll
      for (int j = 0; j < 8; ++j)
        acc[i][j][r] += bi[j] + (float)resid[(size_t)rowg * ND + wn * 128 + j * 16 + lr];
    }
#pragma unroll
  for (int i = 0; i < 2; ++i)
#pragma unroll
    for (int r = 0; r < 4; ++r) {
      float s = 0.f, s2 = 0.f;
#pragma unroll
      for (int j = 0; j < 8; ++j) {
        const float v = acc[i][j][r];
        s += v;
        s2 += v * v;
      }
#pragma unroll
      for (int o = 1; o < 16; o <<= 1) {
        s += __shfl_xor(s, o, 64);
        s2 += __shfl_xor(s2, o, 64);
      }
      if (lr == 0) {
        red[(wid * 32 + i * 16 + hi2 * 4 + r) * 2 + 0] = s;
        red[(wid * 32 + i * 16 + hi2 * 4 + r) * 2 + 1] = s2;
      }
    }
  __syncthreads();
  float g8[8], be8[8];
#pragma unroll
  for (int j = 0; j < 8; ++j) {
    g8[j] = gam[wn * 128 + j * 16 + lr];
    be8[j] = bet[wn * 128 + j * 16 + lr];
  }
#pragma unroll
  for (int i = 0; i < 2; ++i)
#pragma unroll
    for (int r = 0; r < 4; ++r) {
      const int rlw = i * 16 + hi2 * 4 + r;
      float S = 0.f, S2 = 0.f;
#pragma unroll
      for (int q = 0; q < 4; ++q) {
        S += red[((wm * 4 + q) * 32 + rlw) * 2 + 0];
        S2 += red[((wm * 4 + q) * 32 + rlw) * 2 + 1];
      }
      const float mu = S * (1.f / ND);
      const float rstd = rsqrtf(S2 * (1.f / ND) - mu * mu + eps);
      const int rowg = tm * 64 + wm * 32 + rlw;
#pragma unroll
      for (int j = 0; j < 8; ++j) {
        const float ln = (acc[i][j][r] - mu) * rstd * g8[j] + be8[j];
        outB[(size_t)rowg * ND + wn * 128 + j * 16 + lr] = (bf16)ln;
      }
    }
}

// ---------------- LayerNorm: bf16 in -> fp32 out, one wave per row of 512 ----------------
__global__ __launch_bounds__(256) void layernorm_b(
    const bf16* __restrict__ in, const float* __restrict__ gam,
    const float* __restrict__ bet, float eps, float* __restrict__ outf) {
  const int row = blockIdx.x * 4 + (threadIdx.x >> 6);
  const int lane = threadIdx.x & 63;
  const bf16x8 v = ((const bf16x8*)(in + (size_t)row * ND))[lane];
  float f[8];
  float s = 0.f, s2 = 0.f;
#pragma unroll
  for (int e = 0; e < 8; ++e) {
    f[e] = (float)v[e];
    s += f[e];
    s2 += f[e] * f[e];
  }
#pragma unroll
  for (int off = 1; off < 64; off <<= 1) {
    s += __shfl_xor(s, off, 64);
    s2 += __shfl_xor(s2, off, 64);
  }
  const float mu = s * (1.f / ND);
  const float var = s2 * (1.f / ND) - mu * mu;
  const float rstd = rsqrtf(var + eps);
  const float4 g0 = ((const float4*)gam)[lane * 2];
  const float4 g1 = ((const float4*)gam)[lane * 2 + 1];
  const float4 b0 = ((const float4*)bet)[lane * 2];
  const float4 b1 = ((const float4*)bet)[lane * 2 + 1];
  float4 o0, o1;
  o0.x = (f[0] - mu) * rstd * g0.x + b0.x;
  o0.y = (f[1] - mu) * rstd * g0.y + b0.y;
  o0.z = (f[2] - mu) * rstd * g0.z + b0.z;
  o0.w = (f[3] - mu) * rstd * g0.w + b0.w;
  o1.x = (f[4] - mu) * rstd * g1.x + b1.x;
  o1.y = (f[5] - mu) * rstd * g1.y + b1.y;
  o1.z = (f[6] - mu) * rstd * g1.z + b1.z;
  o1.w = (f[7] - mu) * rstd * g1.w + b1.w;
  float* op = outf + (size_t)row * ND;
  ((float4*)op)[lane * 2] = o0;
  ((float4*)op)[lane * 2 + 1] = o1;
}

// ---------------- Flash attention, causal diag -current (r17 best config) ----------------
// QBLK=128: 512 thr = 8 waves, wave w owns q rows [q0+16w, +16). K/V staged once
// per 128 q (1 K-copy + 1 V-copy per wave, vmcnt(2)). Heavy q-blocks first.
// Q pre-scaled by SCL2 at projection -> scores already log2-domain.
// Pw stride 76 bf16: bank advance 6/row -> <=2-way (free) on P path.
__global__ __launch_bounds__(512) void attn_k(
    const bf16* __restrict__ QKg, const bf16* __restrict__ VTg,
    bf16* __restrict__ O, const int* __restrict__ curp) {
  const int current = *curp;
  const int bh = blockIdx.x;
  const int b = bh >> 3, h = bh & 7;
  const int q0 = (gridDim.y - 1 - blockIdx.y) * 128;  // heavy-first dispatch
  const int tid = threadIdx.x, lane = tid & 63, wid = tid >> 6;  // wid 0..7
  const int lr = lane & 15, hi2 = lane >> 4, lk = hi2 * 8;

  __shared__ bf16 Kt[2][64 * 64];
  __shared__ bf16 Vt2[2][64 * 64];
  __shared__ bf16 Pw[8][16 * 76];

  const size_t qoff = (size_t)(b * NS + q0 + wid * 16 + lr) * LDK + h * 64 + lk;
  const bf16x8 aq0 = *(const bf16x8*)&QKg[qoff];
  const bf16x8 aq1 = *(const bf16x8*)&QKg[qoff + 32];

  f32x4 acc[4] = {};
  float m_run = -1e30f, l_run = 0.f;

  int kmax = q0 + 127 - current;
  if (kmax > NS - 1) kmax = NS - 1;
  const int nkt = (kmax >= 0) ? ((kmax >> 6) + 1) : 0;
  const int qv = q0 + wid * 16 + lr;

  const int kchunk = (lane & 7) ^ (lane >> 3);  // K source pre-swizzle
  const int vdv = wid * 8 + (lane >> 3);        // V dest dv row
  const int vkeyc = ((lane & 7) ^ (lane >> 3)) * 8;  // V source key chunk (swz)

  auto stageKV = [&](int kt_, int buf_) {
    const int k0_ = kt_ * 64;
    const int rloc = wid * 8 + (lane >> 3);
    async_copy16(&QKg[(size_t)(b * NS + k0_ + rloc) * LDK + 512 + h * 64 + kchunk * 8],
                 &Kt[buf_][wid * 512]);
    async_copy16(&VTg[(size_t)(h * 64 + vdv) * NTOK + b * NS + k0_ + vkeyc],
                 &Vt2[buf_][wid * 512]);
  };

  if (nkt > 0) stageKV(0, 0);

  for (int kt = 0; kt < nkt; ++kt) {
    const int buf = kt & 1;
    if (kt + 1 < nkt) {
      stageKV(kt + 1, buf ^ 1);
      asm volatile("s_waitcnt vmcnt(2)" ::: "memory");
    } else {
      asm volatile("s_waitcnt vmcnt(0)" ::: "memory");
    }
    __builtin_amdgcn_s_barrier();
    __builtin_amdgcn_sched_barrier(0);

    const int k0 = kt * 64;
    const bf16* Ktb = &Kt[buf][0];
    const bf16* Vtb = &Vt2[buf][0];

    f32x4 sf[4];
    __builtin_amdgcn_s_setprio(1);
#pragma unroll
    for (int kc = 0; kc < 4; ++kc) {
      const int row = kc * 16 + lr;
      const int idx0 = row * 64 + ((hi2 ^ (lr & 7)) << 3);
      f32x4 z = {};
      const bf16x8 bk0 = *(const bf16x8*)&Ktb[idx0];
      const bf16x8 bk1 = *(const bf16x8*)&Ktb[idx0 ^ 32];
      z = __builtin_amdgcn_mfma_f32_16x16x32_bf16(bk0, aq0, z, 0, 0, 0);
      z = __builtin_amdgcn_mfma_f32_16x16x32_bf16(bk1, aq1, z, 0, 0, 0);
      sf[kc] = z;  // already log2-domain (SCL2 folded into Q at projection)
    }
    __builtin_amdgcn_s_setprio(0);

    float sv[16];
    float mx = -1e30f;
    const bool full = (k0 + 63 + current <= q0 + wid * 16);
    if (full) {
#pragma unroll
      for (int kc = 0; kc < 4; ++kc)
#pragma unroll
        for (int r = 0; r < 4; ++r) {
          const float s = sf[kc][r];
          sv[kc * 4 + r] = s;
          mx = fmaxf(mx, s);
        }
    } else {
      const int keyb = k0 + hi2 * 4;
#pragma unroll
      for (int kc = 0; kc < 4; ++kc)
#pragma unroll
        for (int r = 0; r < 4; ++r) {
          const int key = keyb + kc * 16 + r;
          const float s = (key + current <= qv) ? sf[kc][r] : -3.0e38f;
          sv[kc * 4 + r] = s;
          mx = fmaxf(mx, s);
        }
    }
    mx = fmaxf(mx, __shfl_xor(mx, 16, 64));
    mx = fmaxf(mx, __shfl_xor(mx, 32, 64));
    if (__any(mx - m_run > 8.f)) {
      const float mnew = fmaxf(m_run, mx);
      const float sc = __builtin_amdgcn_exp2f(m_run - mnew);
      m_run = mnew;
      l_run *= sc;
#pragma unroll
      for (int j = 0; j < 4; ++j)
#pragma unroll
        for (int r = 0; r < 4; ++r) acc[j][r] *= sc;
    }
    float ps = 0.f;
    bf16x4 pb[4];
#pragma unroll
    for (int kc = 0; kc < 4; ++kc)
#pragma unroll
      for (int r = 0; r < 4; ++r) {
        const float p = __builtin_amdgcn_exp2f(sv[kc * 4 + r] - m_run);
        ps += p;
        pb[kc][r] = (bf16)p;
      }
    ps += __shfl_xor(ps, 16, 64);
    ps += __shfl_xor(ps, 32, 64);
    l_run += ps;
#pragma unroll
    for (int kc = 0; kc < 4; ++kc)
      *(bf16x4*)&Pw[wid][lr * 76 + kc * 16 + hi2 * 4] = pb[kc];

    __builtin_amdgcn_s_setprio(1);
#pragma unroll
    for (int kk = 0; kk < 2; ++kk) {
      const bf16x8 ap = *(const bf16x8*)&Pw[wid][lr * 76 + kk * 32 + lk];
      const int kbase = kk * 4 + hi2;
#pragma unroll
      for (int j = 0; j < 4; ++j) {
        const int dv = j * 16 + lr;
        const bf16x8 bv = *(const bf16x8*)&Vtb[dv * 64 + ((kbase ^ (dv & 7)) << 3)];
        acc[j] = __builtin_amdgcn_mfma_f32_16x16x32_bf16(bv, ap, acc[j], 0, 0, 0);
      }
    }
    __builtin_amdgcn_s_setprio(0);
    __builtin_amdgcn_s_barrier();
    __builtin_amdgcn_sched_barrier(0);
  }

  const float linv = (l_run > 0.f) ? 1.f / l_run : 0.f;
#pragma unroll
  for (int j = 0; j < 4; ++j) {
    bf16x4 ov;
#pragma unroll
    for (int r = 0; r < 4; ++r) ov[r] = (bf16)(acc[j][r] * linv);
    *(bf16x4*)&O[(size_t)(b * NS + qv) * ND + h * 64 + j * 16 + hi2 * 4] = ov;
  }
}

// ---------------- host ----------------
extern "C" void kernel_launch(void* const* d_in, const int* in_sizes, int n_in,
                              void* d_out, int out_size, void* d_ws, size_t ws_size,
                              hipStream_t stream) {
  const float* x = (const float*)d_in[0];
  const float* wq = (const float*)d_in[1];
  const float* bq = (const float*)d_in[2];
  const float* wk = (const float*)d_in[3];
  const float* bk = (const float*)d_in[4];
  const float* wv = (const float*)d_in[5];
  const float* bv = (const float*)d_in[6];
  const float* wfc = (const float*)d_in[7];
  const float* bfc = (const float*)d_in[8];
  const float* ln1g = (const float*)d_in[9];
  const float* ln1b = (const float*)d_in[10];
  const float* w1f = (const float*)d_in[11];
  const float* b1f = (const float*)d_in[12];
  const float* w2f = (const float*)d_in[13];
  const float* b2f = (const float*)d_in[14];
  const float* ln2g = (const float*)d_in[15];
  const float* ln2b = (const float*)d_in[16];
  const int* cur = (const int*)d_in[17];
  float* out = (float*)d_out;

  char* ws = (char*)d_ws;
  size_t off = 0;
  auto alloc = [&](size_t bytes) {
    void* p = ws + off;
    off += (bytes + 255) & ~(size_t)255;
    return p;
  };
  bf16* xb = (bf16*)alloc((size_t)NTOK * ND * 2);     // bf16 x (kept intact; gemm_ln resid)
  bf16* AO = (bf16*)alloc((size_t)NTOK * ND * 2);     // attention output
  bf16* w3b = (bf16*)alloc((size_t)3 * ND * ND * 2);  // [wq;wk;wv]
  bf16* wfcb = (bf16*)alloc((size_t)ND * ND * 2);
  bf16* w1fb = (bf16*)alloc((size_t)NDFF * ND * 2);
  bf16* w2fb = (bf16*)alloc((size_t)ND * NDFF * 2);
  float* b3 = (float*)alloc((size_t)3 * ND * 4);
  bf16* qkb = (bf16*)alloc((size_t)NTOK * LDK * 2);  // reused as ln1 bf16
  bf16* VTg = (bf16*)alloc((size_t)ND * NTOK * 2);   // V^T [512][16384]
  bf16* hb = (bf16*)alloc((size_t)NTOK * NDFF * 2);
  bf16* sum2 = (bf16*)alloc((size_t)NTOK * ND * 2);  // pre-LN2 sum (bf16)
  bf16* ln1bb = qkb;  // LN1 output bf16: FFN1 input AND FFN2 residual

  cvt_all<<<dim3(11264), dim3(256), 0, stream>>>(x, wq, wk, wv, wfc, w1f, w2f,
                                                 xb, w3b, wfcb, w1fb, w2fb);
  concat3<<<dim3(1), dim3(512), 0, stream>>>(bq, bk, bv, b3);

  // fused QKV projection: QK -> qkb (stride 1024, Q pre-scaled), V -> VTg transposed
  gemm_bt<false, true, false><<<dim3(1536 / 128, NTOK / 256), dim3(512), 0, stream>>>(
      xb, w3b, b3, qkb, VTg, nullptr, NTOK, 1536, ND);
  // attention -> AO (QBLK=128, 8 waves)
  attn_k<<<dim3(NB * NH, NS / 128), dim3(512), 0, stream>>>(qkb, VTg, AO, cur);
  // fc + resid(xb bf16) + LN1 -> ln1bb (bf16, single write)
  gemm_ln<<<dim3(NTOK / 64), dim3(512), 0, stream>>>(
      AO, wfcb, bfc, xb, ln1bb, ln1g, ln1b, 1e-5f, ND);
  // FFN1 + ReLU -> hb (bf16)
  gemm_bt<true, false, false><<<dim3(NDFF / 128, NTOK / 256), dim3(512), 0, stream>>>(
      ln1bb, w1fb, b1f, hb, nullptr, nullptr, NTOK, NDFF, ND);
  // FFN2 + resid(ln1 bf16) -> sum2 (bf16)
  gemm_bt<false, false, true><<<dim3(ND / 128, NTOK / 256), dim3(512), 0, stream>>>(
      hb, w2fb, b2f, sum2, nullptr, ln1bb, NTOK, ND, NDFF);
  // LN2: bf16 in -> fp32 out
  layernorm_b<<<dim3(NTOK / 4), dim3(256), 0, stream>>>(sum2, ln2g, ln2b, 1e-6f, out);
}

// Round 21
// 206.972 us; speedup vs baseline: 1.0262x; 1.0009x over previous
//
#include <hip/hip_runtime.h>
#include <hip/hip_bf16.h>
#include <stdint.h>
#include <stddef.h>

#define NB 16
#define NS 1024
#define ND 512
#define NH 8
#define NDFF 2048
#define NTOK (NB * NS)
#define LDK 1024  // fused QK row stride

typedef __bf16 bf16;
typedef __attribute__((ext_vector_type(2))) __bf16 bf16x2;
typedef __attribute__((ext_vector_type(4))) __bf16 bf16x4;
typedef __attribute__((ext_vector_type(8))) __bf16 bf16x8;
typedef __attribute__((ext_vector_type(4))) float f32x4;

__device__ __forceinline__ void async_copy16(const void* g, void* l) {
  __builtin_amdgcn_global_load_lds(
      (const __attribute__((address_space(1))) void*)g,
      (__attribute__((address_space(3))) void*)l,
      16, 0, 0);
}

// ---------------- all fp32 -> bf16 conversions in one kernel ----------------
__global__ __launch_bounds__(256) void cvt_all(
    const float* __restrict__ x, const float* __restrict__ wq,
    const float* __restrict__ wk, const float* __restrict__ wv,
    const float* __restrict__ wfc, const float* __restrict__ w1f,
    const float* __restrict__ w2f,
    bf16* __restrict__ xb, bf16* __restrict__ w3b,
    bf16* __restrict__ wfcb, bf16* __restrict__ w1fb, bf16* __restrict__ w2fb) {
  constexpr int C0 = 2097152, C1 = C0 + 65536, C2 = C1 + 65536, C3 = C2 + 65536,
                C4 = C3 + 65536, C5 = C4 + 262144;
  const int i = blockIdx.x * 256 + threadIdx.x;
  const float* s;
  bf16* d;
  int base;
  if (i < C0)      { s = x;   d = xb;            base = 0;  }
  else if (i < C1) { s = wq;  d = w3b;           base = C0; }
  else if (i < C2) { s = wk;  d = w3b + 262144;  base = C1; }
  else if (i < C3) { s = wv;  d = w3b + 524288;  base = C2; }
  else if (i < C4) { s = wfc; d = wfcb;          base = C3; }
  else if (i < C5) { s = w1f; d = w1fb;          base = C4; }
  else             { s = w2f; d = w2fb;          base = C5; }
  const int k = i - base;
  const float4 v = ((const float4*)s)[k];
  bf16x4 o = {(bf16)v.x, (bf16)v.y, (bf16)v.z, (bf16)v.w};
  ((bf16x4*)d)[k] = o;
}

// ---------------- concat 3 bias vectors (512 each) ----------------
__global__ __launch_bounds__(512) void concat3(const float* __restrict__ a,
                                               const float* __restrict__ b,
                                               const float* __restrict__ c,
                                               float* __restrict__ o) {
  const int t = threadIdx.x;
  o[t] = a[t];
  o[512 + t] = b[t];
  o[1024 + t] = c[t];
}

// LDS chunk swizzle: within a 16-row x 4-chunk (64B-row) segment, slot (r,c)
// holds global chunk c ^ ((r>>1)&3) (source-pre-swizzled, rule 21).
__device__ __forceinline__ int swz_src_col(int lane) {
  const int r = lane >> 2, c = lane & 3;
  return (c ^ ((r >> 1) & 3)) * 8;
}

// ---------------- GEMM 256x128, BK=32, 512 thr = 8 waves, wave 64x64 ----------------
// Ring-of-3 LDS (72 KB), ONE barrier per K-step: vmcnt(3) -> barrier ->
// issue stage(t+2) -> ds_read+MFMA (setprio-wrapped). 2 blocks/CU.
// QKV mode: N=1536; cols<512 (Q) scaled by SCL2; cols<1024 -> qkb (stride 1024);
//           cols>=1024 -> V^T to Cvt.
// RESB mode: bf16 out = acc + bias + bf16 residual (pre-LN2 sum).
template <bool RELU, bool QKV, bool RESB>
__global__ __launch_bounds__(512, 4) void gemm_bt(
    const bf16* __restrict__ A, const bf16* __restrict__ Bw,
    const float* __restrict__ bias, bf16* __restrict__ Cb,
    bf16* __restrict__ Cvt, const bf16* __restrict__ residb,
    int M, int N, int K) {
  __shared__ bf16 As[3][256 * 32];  // 16 KB per buffer
  __shared__ bf16 Bs[3][128 * 32];  // 8 KB per buffer
  const int tid = threadIdx.x;
  const int lane = tid & 63;
  const int wid = tid >> 6;  // 0..7

  const int nwg = gridDim.x * gridDim.y;
  int id = blockIdx.y * gridDim.x + blockIdx.x;
  id = (id & 7) * (nwg >> 3) + (id >> 3);
  const int tn = id % gridDim.x, tm = id / gridDim.x;

  const int wm = wid >> 1, wn = wid & 1;  // wave tile: rows wm*64, cols wn*64
  const int lr = lane & 15, hi2 = lane >> 4;
  const int lkA = ((hi2 ^ ((lr >> 1) & 3)) << 3);  // swizzled read chunk
  const int srow = lane >> 2, scol = swz_src_col(lane);

  f32x4 acc[4][4] = {};

  const bf16* Abase = A + (size_t)(tm * 256 + srow) * K + scol;
  const bf16* Bbase = Bw + (size_t)(tn * 128 + srow) * K + scol;
  const int kiters = K >> 5;

  // 24 chunk-copies (16 A segs + 8 B segs), 3 per wave
  auto stage = [&](int buf, int kb) {
#pragma unroll
    for (int t = 0; t < 3; ++t) {
      const int c = wid * 3 + t;
      if (c < 16) {
        async_copy16(Abase + (size_t)c * 16 * K + kb * 32, &As[buf][c * 512]);
      } else {
        const int s = c - 16;
        async_copy16(Bbase + (size_t)s * 16 * K + kb * 32, &Bs[buf][s * 512]);
      }
    }
  };

  stage(0, 0);
  stage(1, 1);

  int rbuf = 0;  // buffer holding tile kb
  int sbuf = 2;  // buffer to stage tile kb+2 into
  for (int kb = 0; kb < kiters; ++kb) {
    if (kb + 1 < kiters) {
      asm volatile("s_waitcnt vmcnt(3)" ::: "memory");  // tile kb landed; kb+1 in flight
    } else {
      asm volatile("s_waitcnt vmcnt(0)" ::: "memory");
    }
    __builtin_amdgcn_s_barrier();
    __builtin_amdgcn_sched_barrier(0);

    if (kb + 2 < kiters) stage(sbuf, kb + 2);  // flies under this step's MFMAs

    bf16x8 af[4], bfr[4];
#pragma unroll
    for (int i = 0; i < 4; ++i)
      af[i] = *(const bf16x8*)&As[rbuf][(wm * 64 + i * 16 + lr) * 32 + lkA];
#pragma unroll
    for (int j = 0; j < 4; ++j)
      bfr[j] = *(const bf16x8*)&Bs[rbuf][(wn * 64 + j * 16 + lr) * 32 + lkA];
    __builtin_amdgcn_s_setprio(1);
#pragma unroll
    for (int i = 0; i < 4; ++i)
#pragma unroll
      for (int j = 0; j < 4; ++j)
        acc[i][j] = __builtin_amdgcn_mfma_f32_16x16x32_bf16(af[i], bfr[j], acc[i][j], 0, 0, 0);
    __builtin_amdgcn_s_setprio(0);

    rbuf = (rbuf == 2) ? 0 : rbuf + 1;
    sbuf = (sbuf == 2) ? 0 : sbuf + 1;
  }

  const float SCL2 = 0.18033688f;  // (1/sqrt(64)) * log2(e) folded into Q
#pragma unroll
  for (int i = 0; i < 4; ++i) {
    const int row0 = tm * 256 + wm * 64 + i * 16 + hi2 * 4;
#pragma unroll
    for (int j = 0; j < 4; ++j) {
      const int col = tn * 128 + wn * 64 + j * 16 + lr;
      const float bcol = bias[col];
      if (QKV && col >= 1024) {
        bf16x4 ov;
#pragma unroll
        for (int r = 0; r < 4; ++r) ov[r] = (bf16)(acc[i][j][r] + bcol);
        *(bf16x4*)&Cvt[(size_t)(col - 1024) * M + row0] = ov;
      } else if (RESB) {
#pragma unroll
        for (int r = 0; r < 4; ++r) {
          const size_t idx = (size_t)(row0 + r) * N + col;
          Cb[idx] = (bf16)(acc[i][j][r] + bcol + (float)residb[idx]);
        }
      } else {
        const int strideN = QKV ? 1024 : N;
#pragma unroll
        for (int r = 0; r < 4; ++r) {
          float c = acc[i][j][r] + bcol;
          if (QKV && col < 512) c *= SCL2;  // pre-scale Q for log2-domain softmax
          if (RELU) c = fmaxf(c, 0.f);
          Cb[(size_t)(row0 + r) * strideN + col] = (bf16)c;
        }
      }
    }
  }
}

// ---------------- GEMM (BM=64, BN=N=512) + bias + bf16 resid + fused LayerNorm ----------------
// K=512 only (fc+LN1). Writes LN output ONCE as bf16 (FFN1 input AND FFN2 resid).
__global__ __launch_bounds__(512) void gemm_ln(
    const bf16* __restrict__ A, const bf16* __restrict__ Bw,
    const float* __restrict__ bias, const bf16* __restrict__ resid,
    bf16* __restrict__ outB,
    const float* __restrict__ gam, const float* __restrict__ bet,
    float eps, int K) {
  __shared__ bf16 As[2][64 * 32];
  __shared__ bf16 Bs[2][512 * 32];
  __shared__ float red[8 * 32 * 2];
  const int tid = threadIdx.x;
  const int lane = tid & 63;
  const int wid = tid >> 6;
  const int wm = wid >> 2, wn = wid & 3;
  const int lr = lane & 15, hi2 = lane >> 4;
  const int lkA = ((hi2 ^ ((lr >> 1) & 3)) << 3);
  const int tm = blockIdx.x;

  f32x4 acc[2][8] = {};
  const int kiters = K >> 5;
  const int r4 = lane >> 2, c4 = swz_src_col(lane);

  auto stage = [&](int buf, int kb) {
    if (wid < 4) {
      async_copy16(A + (size_t)(tm * 64 + wid * 16 + r4) * K + kb * 32 + c4,
                   &As[buf][wid * 16 * 32]);
#pragma unroll
      for (int i = 0; i < 3; ++i) {
        const int s = wid * 3 + i;
        async_copy16(Bw + (size_t)(s * 16 + r4) * K + kb * 32 + c4, &Bs[buf][s * 16 * 32]);
      }
    } else {
#pragma unroll
      for (int i = 0; i < 5; ++i) {
        const int s = 12 + (wid - 4) * 5 + i;
        async_copy16(Bw + (size_t)(s * 16 + r4) * K + kb * 32 + c4, &Bs[buf][s * 16 * 32]);
      }
    }
  };

  stage(0, 0);

  int buf = 0;
  for (int kb = 0; kb < kiters; ++kb) {
    if (kb + 1 < kiters) {
      stage(buf ^ 1, kb + 1);
      if (wid < 4) asm volatile("s_waitcnt vmcnt(4)" ::: "memory");
      else         asm volatile("s_waitcnt vmcnt(5)" ::: "memory");
    } else {
      asm volatile("s_waitcnt vmcnt(0)" ::: "memory");
    }
    __builtin_amdgcn_s_barrier();
    __builtin_amdgcn_sched_barrier(0);

    bf16x8 af[2], bfr[8];
#pragma unroll
    for (int i = 0; i < 2; ++i)
      af[i] = *(const bf16x8*)&As[buf][(wm * 32 + i * 16 + lr) * 32 + lkA];
#pragma unroll
    for (int j = 0; j < 8; ++j)
      bfr[j] = *(const bf16x8*)&Bs[buf][(wn * 128 + j * 16 + lr) * 32 + lkA];
#pragma unroll
    for (int i = 0; i < 2; ++i)
#pragma unroll
      for (int j = 0; j < 8; ++j)
        acc[i][j] = __builtin_amdgcn_mfma_f32_16x16x32_bf16(af[i], bfr[j], acc[i][j], 0, 0, 0);

    __builtin_amdgcn_s_barrier();
    __builtin_amdgcn_sched_barrier(0);
    buf ^= 1;
  }

  float bi[8];
#pragma unroll
  for (int j = 0; j < 8; ++j) bi[j] = bias[wn * 128 + j * 16 + lr];
#pragma unroll
  for (int i = 0; i < 2; ++i)
#pragma unroll
    for (int r = 0; r < 4; ++r) {
      const int rowg = tm * 64 + wm * 32 + i * 16 + hi2 * 4 + r;
#pragma unroll
      for (int j = 0; j < 8; ++j)
        acc[i][j][r] += bi[j] + (float)resid[(size_t)rowg * ND + wn * 128 + j * 16 + lr];
    }
#pragma unroll
  for (int i = 0; i < 2; ++i)
#pragma unroll
    for (int r = 0; r < 4; ++r) {
      float s = 0.f, s2 = 0.f;
#pragma unroll
      for (int j = 0; j < 8; ++j) {
        const float v = acc[i][j][r];
        s += v;
        s2 += v * v;
      }
#pragma unroll
      for (int o = 1; o < 16; o <<= 1) {
        s += __shfl_xor(s, o, 64);
        s2 += __shfl_xor(s2, o, 64);
      }
      if (lr == 0) {
        red[(wid * 32 + i * 16 + hi2 * 4 + r) * 2 + 0] = s;
        red[(wid * 32 + i * 16 + hi2 * 4 + r) * 2 + 1] = s2;
      }
    }
  __syncthreads();
  float g8[8], be8[8];
#pragma unroll
  for (int j = 0; j < 8; ++j) {
    g8[j] = gam[wn * 128 + j * 16 + lr];
    be8[j] = bet[wn * 128 + j * 16 + lr];
  }
#pragma unroll
  for (int i = 0; i < 2; ++i)
#pragma unroll
    for (int r = 0; r < 4; ++r) {
      const int rlw = i * 16 + hi2 * 4 + r;
      float S = 0.f, S2 = 0.f;
#pragma unroll
      for (int q = 0; q < 4; ++q) {
        S += red[((wm * 4 + q) * 32 + rlw) * 2 + 0];
        S2 += red[((wm * 4 + q) * 32 + rlw) * 2 + 1];
      }
      const float mu = S * (1.f / ND);
      const float rstd = rsqrtf(S2 * (1.f / ND) - mu * mu + eps);
      const int rowg = tm * 64 + wm * 32 + rlw;
#pragma unroll
      for (int j = 0; j < 8; ++j) {
        const float ln = (acc[i][j][r] - mu) * rstd * g8[j] + be8[j];
        outB[(size_t)rowg * ND + wn * 128 + j * 16 + lr] = (bf16)ln;
      }
    }
}

// ---------------- LayerNorm: bf16 in -> fp32 out, one wave per row of 512 ----------------
__global__ __launch_bounds__(256) void layernorm_b(
    const bf16* __restrict__ in, const float* __restrict__ gam,
    const float* __restrict__ bet, float eps, float* __restrict__ outf) {
  const int row = blockIdx.x * 4 + (threadIdx.x >> 6);
  const int lane = threadIdx.x & 63;
  const bf16x8 v = ((const bf16x8*)(in + (size_t)row * ND))[lane];
  float f[8];
  float s = 0.f, s2 = 0.f;
#pragma unroll
  for (int e = 0; e < 8; ++e) {
    f[e] = (float)v[e];
    s += f[e];
    s2 += f[e] * f[e];
  }
#pragma unroll
  for (int off = 1; off < 64; off <<= 1) {
    s += __shfl_xor(s, off, 64);
    s2 += __shfl_xor(s2, off, 64);
  }
  const float mu = s * (1.f / ND);
  const float var = s2 * (1.f / ND) - mu * mu;
  const float rstd = rsqrtf(var + eps);
  const float4 g0 = ((const float4*)gam)[lane * 2];
  const float4 g1 = ((const float4*)gam)[lane * 2 + 1];
  const float4 b0 = ((const float4*)bet)[lane * 2];
  const float4 b1 = ((const float4*)bet)[lane * 2 + 1];
  float4 o0, o1;
  o0.x = (f[0] - mu) * rstd * g0.x + b0.x;
  o0.y = (f[1] - mu) * rstd * g0.y + b0.y;
  o0.z = (f[2] - mu) * rstd * g0.z + b0.z;
  o0.w = (f[3] - mu) * rstd * g0.w + b0.w;
  o1.x = (f[4] - mu) * rstd * g1.x + b1.x;
  o1.y = (f[5] - mu) * rstd * g1.y + b1.y;
  o1.z = (f[6] - mu) * rstd * g1.z + b1.z;
  o1.w = (f[7] - mu) * rstd * g1.w + b1.w;
  float* op = outf + (size_t)row * ND;
  ((float4*)op)[lane * 2] = o0;
  ((float4*)op)[lane * 2 + 1] = o1;
}

// ---------------- Flash attention, causal diag -current (r17 best config) ----------------
// QBLK=128: 512 thr = 8 waves, wave w owns q rows [q0+16w, +16). K/V staged once
// per 128 q (1 K-copy + 1 V-copy per wave, vmcnt(2)). Heavy q-blocks first.
// Q pre-scaled by SCL2 at projection -> scores already log2-domain.
// Pw stride 76 bf16: bank advance 6/row -> <=2-way (free) on P path.
__global__ __launch_bounds__(512) void attn_k(
    const bf16* __restrict__ QKg, const bf16* __restrict__ VTg,
    bf16* __restrict__ O, const int* __restrict__ curp) {
  const int current = *curp;
  const int bh = blockIdx.x;
  const int b = bh >> 3, h = bh & 7;
  const int q0 = (gridDim.y - 1 - blockIdx.y) * 128;  // heavy-first dispatch
  const int tid = threadIdx.x, lane = tid & 63, wid = tid >> 6;  // wid 0..7
  const int lr = lane & 15, hi2 = lane >> 4, lk = hi2 * 8;

  __shared__ bf16 Kt[2][64 * 64];
  __shared__ bf16 Vt2[2][64 * 64];
  __shared__ bf16 Pw[8][16 * 76];

  const size_t qoff = (size_t)(b * NS + q0 + wid * 16 + lr) * LDK + h * 64 + lk;
  const bf16x8 aq0 = *(const bf16x8*)&QKg[qoff];
  const bf16x8 aq1 = *(const bf16x8*)&QKg[qoff + 32];

  f32x4 acc[4] = {};
  float m_run = -1e30f, l_run = 0.f;

  int kmax = q0 + 127 - current;
  if (kmax > NS - 1) kmax = NS - 1;
  const int nkt = (kmax >= 0) ? ((kmax >> 6) + 1) : 0;
  const int qv = q0 + wid * 16 + lr;

  const int kchunk = (lane & 7) ^ (lane >> 3);  // K source pre-swizzle
  const int vdv = wid * 8 + (lane >> 3);        // V dest dv row
  const int vkeyc = ((lane & 7) ^ (lane >> 3)) * 8;  // V source key chunk (swz)

  auto stageKV = [&](int kt_, int buf_) {
    const int k0_ = kt_ * 64;
    const int rloc = wid * 8 + (lane >> 3);
    async_copy16(&QKg[(size_t)(b * NS + k0_ + rloc) * LDK + 512 + h * 64 + kchunk * 8],
                 &Kt[buf_][wid * 512]);
    async_copy16(&VTg[(size_t)(h * 64 + vdv) * NTOK + b * NS + k0_ + vkeyc],
                 &Vt2[buf_][wid * 512]);
  };

  if (nkt > 0) stageKV(0, 0);

  for (int kt = 0; kt < nkt; ++kt) {
    const int buf = kt & 1;
    if (kt + 1 < nkt) {
      stageKV(kt + 1, buf ^ 1);
      asm volatile("s_waitcnt vmcnt(2)" ::: "memory");
    } else {
      asm volatile("s_waitcnt vmcnt(0)" ::: "memory");
    }
    __builtin_amdgcn_s_barrier();
    __builtin_amdgcn_sched_barrier(0);

    const int k0 = kt * 64;
    const bf16* Ktb = &Kt[buf][0];
    const bf16* Vtb = &Vt2[buf][0];

    f32x4 sf[4];
    __builtin_amdgcn_s_setprio(1);
#pragma unroll
    for (int kc = 0; kc < 4; ++kc) {
      const int row = kc * 16 + lr;
      const int idx0 = row * 64 + ((hi2 ^ (lr & 7)) << 3);
      f32x4 z = {};
      const bf16x8 bk0 = *(const bf16x8*)&Ktb[idx0];
      const bf16x8 bk1 = *(const bf16x8*)&Ktb[idx0 ^ 32];
      z = __builtin_amdgcn_mfma_f32_16x16x32_bf16(bk0, aq0, z, 0, 0, 0);
      z = __builtin_amdgcn_mfma_f32_16x16x32_bf16(bk1, aq1, z, 0, 0, 0);
      sf[kc] = z;  // already log2-domain (SCL2 folded into Q at projection)
    }
    __builtin_amdgcn_s_setprio(0);

    float sv[16];
    float mx = -1e30f;
    const bool full = (k0 + 63 + current <= q0 + wid * 16);
    if (full) {
#pragma unroll
      for (int kc = 0; kc < 4; ++kc)
#pragma unroll
        for (int r = 0; r < 4; ++r) {
          const float s = sf[kc][r];
          sv[kc * 4 + r] = s;
          mx = fmaxf(mx, s);
        }
    } else {
      const int keyb = k0 + hi2 * 4;
#pragma unroll
      for (int kc = 0; kc < 4; ++kc)
#pragma unroll
        for (int r = 0; r < 4; ++r) {
          const int key = keyb + kc * 16 + r;
          const float s = (key + current <= qv) ? sf[kc][r] : -3.0e38f;
          sv[kc * 4 + r] = s;
          mx = fmaxf(mx, s);
        }
    }
    mx = fmaxf(mx, __shfl_xor(mx, 16, 64));
    mx = fmaxf(mx, __shfl_xor(mx, 32, 64));
    if (__any(mx - m_run > 8.f)) {
      const float mnew = fmaxf(m_run, mx);
      const float sc = __builtin_amdgcn_exp2f(m_run - mnew);
      m_run = mnew;
      l_run *= sc;
#pragma unroll
      for (int j = 0; j < 4; ++j)
#pragma unroll
        for (int r = 0; r < 4; ++r) acc[j][r] *= sc;
    }
    float ps = 0.f;
    bf16x4 pb[4];
#pragma unroll
    for (int kc = 0; kc < 4; ++kc)
#pragma unroll
      for (int r = 0; r < 4; ++r) {
        const float p = __builtin_amdgcn_exp2f(sv[kc * 4 + r] - m_run);
        ps += p;
        pb[kc][r] = (bf16)p;
      }
    ps += __shfl_xor(ps, 16, 64);
    ps += __shfl_xor(ps, 32, 64);
    l_run += ps;
#pragma unroll
    for (int kc = 0; kc < 4; ++kc)
      *(bf16x4*)&Pw[wid][lr * 76 + kc * 16 + hi2 * 4] = pb[kc];

    __builtin_amdgcn_s_setprio(1);
#pragma unroll
    for (int kk = 0; kk < 2; ++kk) {
      const bf16x8 ap = *(const bf16x8*)&Pw[wid][lr * 76 + kk * 32 + lk];
      const int kbase = kk * 4 + hi2;
#pragma unroll
      for (int j = 0; j < 4; ++j) {
        const int dv = j * 16 + lr;
        const bf16x8 bv = *(const bf16x8*)&Vtb[dv * 64 + ((kbase ^ (dv & 7)) << 3)];
        acc[j] = __builtin_amdgcn_mfma_f32_16x16x32_bf16(bv, ap, acc[j], 0, 0, 0);
      }
    }
    __builtin_amdgcn_s_setprio(0);
    __builtin_amdgcn_s_barrier();
    __builtin_amdgcn_sched_barrier(0);
  }

  const float linv = (l_run > 0.f) ? 1.f / l_run : 0.f;
#pragma unroll
  for (int j = 0; j < 4; ++j) {
    bf16x4 ov;
#pragma unroll
    for (int r = 0; r < 4; ++r) ov[r] = (bf16)(acc[j][r] * linv);
    *(bf16x4*)&O[(size_t)(b * NS + qv) * ND + h * 64 + j * 16 + hi2 * 4] = ov;
  }
}

// ---------------- host ----------------
extern "C" void kernel_launch(void* const* d_in, const int* in_sizes, int n_in,
                              void* d_out, int out_size, void* d_ws, size_t ws_size,
                              hipStream_t stream) {
  const float* x = (const float*)d_in[0];
  const float* wq = (const float*)d_in[1];
  const float* bq = (const float*)d_in[2];
  const float* wk = (const float*)d_in[3];
  const float* bk = (const float*)d_in[4];
  const float* wv = (const float*)d_in[5];
  const float* bv = (const float*)d_in[6];
  const float* wfc = (const float*)d_in[7];
  const float* bfc = (const float*)d_in[8];
  const float* ln1g = (const float*)d_in[9];
  const float* ln1b = (const float*)d_in[10];
  const float* w1f = (const float*)d_in[11];
  const float* b1f = (const float*)d_in[12];
  const float* w2f = (const float*)d_in[13];
  const float* b2f = (const float*)d_in[14];
  const float* ln2g = (const float*)d_in[15];
  const float* ln2b = (const float*)d_in[16];
  const int* cur = (const int*)d_in[17];
  float* out = (float*)d_out;

  char* ws = (char*)d_ws;
  size_t off = 0;
  auto alloc = [&](size_t bytes) {
    void* p = ws + off;
    off += (bytes + 255) & ~(size_t)255;
    return p;
  };
  bf16* xb = (bf16*)alloc((size_t)NTOK * ND * 2);     // bf16 x (kept intact; gemm_ln resid)
  bf16* AO = (bf16*)alloc((size_t)NTOK * ND * 2);     // attention output
  bf16* w3b = (bf16*)alloc((size_t)3 * ND * ND * 2);  // [wq;wk;wv]
  bf16* wfcb = (bf16*)alloc((size_t)ND * ND * 2);
  bf16* w1fb = (bf16*)alloc((size_t)NDFF * ND * 2);
  bf16* w2fb = (bf16*)alloc((size_t)ND * NDFF * 2);
  float* b3 = (float*)alloc((size_t)3 * ND * 4);
  bf16* qkb = (bf16*)alloc((size_t)NTOK * LDK * 2);  // reused as ln1 bf16
  bf16* VTg = (bf16*)alloc((size_t)ND * NTOK * 2);   // V^T [512][16384]
  bf16* hb = (bf16*)alloc((size_t)NTOK * NDFF * 2);
  bf16* sum2 = (bf16*)alloc((size_t)NTOK * ND * 2);  // pre-LN2 sum (bf16)
  bf16* ln1bb = qkb;  // LN1 output bf16: FFN1 input AND FFN2 residual

  cvt_all<<<dim3(11264), dim3(256), 0, stream>>>(x, wq, wk, wv, wfc, w1f, w2f,
                                                 xb, w3b, wfcb, w1fb, w2fb);
  concat3<<<dim3(1), dim3(512), 0, stream>>>(bq, bk, bv, b3);

  // fused QKV projection: QK -> qkb (stride 1024, Q pre-scaled), V -> VTg transposed
  gemm_bt<false, true, false><<<dim3(1536 / 128, NTOK / 256), dim3(512), 0, stream>>>(
      xb, w3b, b3, qkb, VTg, nullptr, NTOK, 1536, ND);
  // attention -> AO (QBLK=128, 8 waves)
  attn_k<<<dim3(NB * NH, NS / 128), dim3(512), 0, stream>>>(qkb, VTg, AO, cur);
  // fc + resid(xb bf16) + LN1 -> ln1bb (bf16, single write)
  gemm_ln<<<dim3(NTOK / 64), dim3(512), 0, stream>>>(
      AO, wfcb, bfc, xb, ln1bb, ln1g, ln1b, 1e-5f, ND);
  // FFN1 + ReLU -> hb (bf16)
  gemm_bt<true, false, false><<<dim3(NDFF / 128, NTOK / 256), dim3(512), 0, stream>>>(
      ln1bb, w1fb, b1f, hb, nullptr, nullptr, NTOK, NDFF, ND);
  // FFN2 + resid(ln1 bf16) -> sum2 (bf16)
  gemm_bt<false, false, true><<<dim3(ND / 128, NTOK / 256), dim3(512), 0, stream>>>(
      hb, w2fb, b2f, sum2, nullptr, ln1bb, NTOK, ND, NDFF);
  // LN2: bf16 in -> fp32 out
  layernorm_b<<<dim3(NTOK / 4), dim3(256), 0, stream>>>(sum2, ln2g, ln2b, 1e-6f, out);
}